// Round 14
// baseline (653.193 us; speedup 1.0000x reference)
//
#include <hip/hip_runtime.h>
#include <hip/hip_bf16.h>
#include <math.h>

#define HWN 6400
#define CC 256
#define MIDN 64
#define NCG 64   // channel groups for edge/period pass (4 ch each)

typedef _Float16 f16x8 __attribute__((ext_vector_type(8)));
typedef _Float16 f16x4 __attribute__((ext_vector_type(4)));
typedef _Float16 h2    __attribute__((ext_vector_type(2)));
typedef float    f32x4 __attribute__((ext_vector_type(4)));
typedef int      i32x4 __attribute__((ext_vector_type(4)));

__device__ __forceinline__ h2 pk2(float a, float b) {
    return __builtin_bit_cast(h2, __builtin_amdgcn_cvt_pkrtz(a, b));
}
__device__ __forceinline__ float h2lo(h2 v) { return (float)v[0]; }
__device__ __forceinline__ float h2hi(h2 v) { return (float)v[1]; }
__device__ __forceinline__ unsigned h2u(h2 v) { return __builtin_bit_cast(unsigned, v); }
__device__ __forceinline__ h2 u2h(unsigned u) { return __builtin_bit_cast(h2, u); }
__device__ __forceinline__ float vsqrtf_(float x) { float r; asm("v_sqrt_f32 %0, %1" : "=v"(r) : "v"(x)); return r; }

// ---------------- K0: fold BN, pack MFMA A-fragments (fp16) ----------------
__global__ void prep_kernel(const float* __restrict__ proj_w,
                            const float* __restrict__ g1, const float* __restrict__ b1,
                            const float* __restrict__ m1, const float* __restrict__ v1,
                            const float* __restrict__ f1w,
                            const float* __restrict__ g2, const float* __restrict__ b2,
                            const float* __restrict__ m2, const float* __restrict__ v2,
                            _Float16* __restrict__ apack_proj,
                            _Float16* __restrict__ apack_fuse,
                            float* __restrict__ bias1, float* __restrict__ bias2) {
    int gid = blockIdx.x * blockDim.x + threadIdx.x;
    int stride = gridDim.x * blockDim.x;
    if (gid < MIDN) {
        float s1 = g1[gid] * rsqrtf(v1[gid] + 1e-5f);
        bias1[gid] = b1[gid] - m1[gid] * s1;
        float s2 = g2[gid] * rsqrtf(v2[gid] + 1e-5f);
        bias2[gid] = b2[gid] - m2[gid] * s2;
    }
    for (int i = gid; i < 8 * 4 * 64 * 8; i += stride) {
        int j = i & 7, lane = (i >> 3) & 63, w = (i >> 9) & 3, c = i >> 11;
        int m = w * 16 + (lane & 15);
        int ch = c * 32 + (lane >> 4) * 8 + j;
        float s1 = g1[m] * rsqrtf(v1[m] + 1e-5f);
        apack_proj[i] = (_Float16)(proj_w[m * CC + ch] * s1);
    }
    for (int i = gid; i < 9 * 3 * 4 * 64 * 8; i += stride) {
        int j = i & 7, lane = (i >> 3) & 63, w = (i >> 9) & 3;
        int tc = i >> 11; int c = tc % 3, t = tc / 3;
        int m = w * 16 + (lane & 15);
        int ch = c * 32 + (lane >> 4) * 8 + j;
        float s2 = g2[m] * rsqrtf(v2[m] + 1e-5f);
        float v = 0.f;
        if (ch < 66) v = f1w[(m * 66 + ch) * 9 + t] * s2;
        apack_fuse[i] = (_Float16)v;
    }
}

// ---------------- K1: edge + period, wave-band column-march, prefetched ----------------
// grid (NCG=64 cg, 16 b), 512 thr = 8 waves; wave w owns rows [10w,10w+10),
// lane l owns cols {l, 64+l(l<16)}; 4 channels/block. No __syncthreads;
// wb volatile (order preserved; per-wave DS queue in-order), no fences so
// loads pipeline. er/pr accumulators packed h2 to push VGPR below the
// 64-reg occupancy cliff (target: 32 waves/CU with 4 blocks/CU).
__launch_bounds__(512, 8)
__global__ void edge_period_kernel(const float* __restrict__ x,
                                   unsigned* __restrict__ part) {
    __shared__ unsigned wb[8][88];
    volatile unsigned (*wbv)[88] = wb;
    int tid = threadIdx.x;
    int w = tid >> 6, l = tid & 63;
    int b = blockIdx.y, cg = blockIdx.x;
    int row0 = w * 10;
    int im1 = (l + 63) & 63, ip1 = (l + 1) & 63;
    bool is0 = (l == 0), is63 = (l == 63), isB = (l < 16);

    if (l < 4) wbv[w][(l < 2) ? l : 80 + l] = 0u;   // zero pad cols idx 0,1,82,83

    // column resize weights (0.5 of Haar folded in)
    float cwA = (l <= 0) ? 1.f : ((l >= 79) ? 0.f : (0.99375f - 0.0125f * (float)l));
    int cB = 64 + l;
    float cwB = (cB >= 79) ? 0.f : (0.99375f - 0.0125f * (float)cB);
    h2 v_pk = pk2(0.5f * cwA, 0.5f * cwB);
    h2 u_pk = pk2(0.5f * (1.f - cwA), 0.5f * (1.f - cwB));

    h2 erh[10], prh[10];
#pragma unroll
    for (int k = 0; k < 10; k++) { erh[k] = u2h(0u); prh[k] = u2h(0u); }

#pragma unroll 1
    for (int ch = 0; ch < 4; ch++) {
        const float* xch = x + ((size_t)(b * CC + cg * 4 + ch)) * HWN;
        auto rawload = [&](int rr, float& a, float& bb) {
            a = 0.f; bb = 0.f;
            if (rr >= 0 && rr < 80) {
                a = xch[rr * 80 + l];
                if (isB) bb = xch[rr * 80 + 64 + l];
            }
        };
        auto mktrip = [&](float a, float bb, h2& t0, h2& t1, h2& t2) {
            h2 xc = pk2(a, bb);
            int xi = __builtin_bit_cast(int, xc);
            unsigned um = (unsigned)__shfl(xi, im1);
            unsigned up = (unsigned)__shfl(xi, ip1);
            um = is0 ? ((um & 0xFFFFu) << 16) : um;   // lane0: {0, col63}
            up = is63 ? (up >> 16) : up;              // lane63: {col64, 0}
            t0 = u2h(um); t1 = xc; t2 = u2h(up);
        };
        h2 xm1_0, xm1_1, xm1_2, x0_0, x0_1, x0_2, xp1_0, xp1_1, xp1_2;
        float ta, tb, ra, rb, na, nb;
        rawload(row0 - 3, ta, tb);
        rawload(row0 - 2, ra, rb);
        mktrip(ta, tb, xm1_0, xm1_1, xm1_2);
        mktrip(ra, rb, x0_0, x0_1, x0_2);
        rawload(row0 - 1, ra, rb);          // raw row for s=0's xp1
        // seam init: lhc_p/hlc_p = column-resized haar at row pair (row0-3, row0-2)
        h2 lhc_p, hlc_p;
        {
            h2 sa = xm1_0 + x0_0, sb = xm1_1 + x0_1, sc2 = xm1_2 + x0_2;
            h2 da = xm1_0 - x0_0, db = xm1_1 - x0_1, dc = xm1_2 - x0_2;
            lhc_p = u_pk * (sa - sb) + v_pk * (sb - sc2);
            hlc_p = u_pk * (da + db) + v_pk * (db + dc);
        }
        h2 ringA[5], ringB[5];
        float ringSA[5], ringSB[5];
#pragma unroll
        for (int s = 0; s < 14; s++) {
            int r = row0 - 2 + s;
            // issue next raw row load early (consumed next iteration)
            if (s < 13) rawload(row0 + s, na, nb);
            // convert + shuffle the row loaded last iteration (full iter of slack)
            mktrip(ra, rb, xp1_0, xp1_1, xp1_2);
            // Sobel (own rows only; r in [row0,row0+10) guaranteed for s in [2,12))
            if (s >= 2 && s < 12) {
                h2 gx = (xm1_2 - xm1_0) + (x0_2 - x0_0) + (x0_2 - x0_0) + (xp1_2 - xp1_0);
                h2 gy = (xp1_0 - xm1_0) + (xp1_1 - xm1_1) + (xp1_1 - xm1_1) + (xp1_2 - xm1_2);
                h2 g2v = gx * gx + gy * gy;
                erh[s - 2] += pk2(vsqrtf_(h2lo(g2v)) * 0.125f, vsqrtf_(h2hi(g2v)) * 0.125f);
            }
            // Haar row pair (r, r+1) -> column-resized lh/hl, then row-resize
            h2 sa = x0_0 + xp1_0, sb = x0_1 + xp1_1, sc2 = x0_2 + xp1_2;
            h2 da = x0_0 - xp1_0, db = x0_1 - xp1_1, dc = x0_2 - xp1_2;
            h2 lhc = u_pk * (sa - sb) + v_pk * (sb - sc2);
            h2 hlc = u_pk * (da + db) + v_pk * (db + dc);
            float cw = (r <= 0) ? 1.f : ((r >= 79) ? 0.f : (0.99375f - 0.0125f * (float)r));
            h2 cwp = pk2(cw, cw), pwp = pk2(1.f - cw, 1.f - cw);
            h2 lhr = pwp * lhc_p + cwp * lhc;
            h2 hlr = pwp * hlc_p + cwp * hlc;
            lhc_p = lhc; hlc_p = hlc;
            unsigned lu = h2u(lhr), hu = h2u(hlr);
            unsigned fA = (lu & 0xFFFFu) | (hu << 16);           // {lh,hl} col l
            unsigned fB = (lu >> 16) | (hu & 0xFFFF0000u);       // {lh,hl} col 64+l
            bool fv = (r >= 0) && (r < 80);
            if (!fv) { fA = 0u; fB = 0u; }
            // horizontal 5-sum via per-wave LDS row (volatile keeps write->read
            // order; same-wave DS pipe executes in order)
            wbv[w][2 + l] = fA;
            if (isB) wbv[w][66 + l] = fB;
            unsigned am2 = wbv[w][l], am1 = wbv[w][l + 1], ap1 = wbv[w][l + 3], ap2 = wbv[w][l + 4];
            unsigned bm2 = 0, bm1 = 0, bp1 = 0, bp2 = 0;
            if (isB) { bm2 = wbv[w][64 + l]; bm1 = wbv[w][65 + l]; bp1 = wbv[w][67 + l]; bp2 = wbv[w][68 + l]; }
            h2 fAh = u2h(fA), fBh = u2h(fB);
            h2 n0 = u2h(am2), n1 = u2h(am1), n2 = u2h(ap1), n3 = u2h(ap2);
            h2 hA = fAh + n0 + n1 + n2 + n3;
            h2 qa = fAh * fAh + n0 * n0 + n1 * n1 + n2 * n2 + n3 * n3;
            float s2A = h2lo(qa) + h2hi(qa);
            h2 m0 = u2h(bm2), m1 = u2h(bm1), m2 = u2h(bp1), m3 = u2h(bp2);
            h2 hB = fBh + m0 + m1 + m2 + m3;
            h2 qb = fBh * fBh + m0 * m0 + m1 * m1 + m2 * m2 + m3 * m3;
            float s2B = h2lo(qb) + h2hi(qb);
            ringA[s % 5] = hA; ringB[s % 5] = hB;
            ringSA[s % 5] = s2A; ringSB[s % 5] = s2B;
            // vertical 5-sum + variance + period emit at row i = r-2
            if (s >= 4) {
                h2 SA = ringA[0] + ringA[1] + ringA[2] + ringA[3] + ringA[4];
                h2 SB = ringB[0] + ringB[1] + ringB[2] + ringB[3] + ringB[4];
                float S2A = ringSA[0] + ringSA[1] + ringSA[2] + ringSA[3] + ringSA[4];
                float S2B = ringSB[0] + ringSB[1] + ringSB[2] + ringSB[3] + ringSB[4];
                float SLA = h2lo(SA), SHA = h2hi(SA);
                float SLB = h2lo(SB), SHB = h2hi(SB);
                float vA = 0.04f * S2A - 0.0016f * (SLA * SLA + SHA * SHA);
                float vB = 0.04f * S2B - 0.0016f * (SLB * SLB + SHB * SHB);
                vA = fmaxf(vA, 0.f) + 1e-6f;
                vB = fmaxf(vB, 0.f) + 1e-6f;
                prh[s - 4] += pk2(vsqrtf_(vA), vsqrtf_(vB));
            }
            xm1_0 = x0_0; xm1_1 = x0_1; xm1_2 = x0_2;
            x0_0 = xp1_0; x0_1 = xp1_1; x0_2 = xp1_2;
            ra = na; rb = nb;
        }
    }
    size_t base = ((size_t)(cg * 16 + b) * 80 + row0) * 80;
#pragma unroll
    for (int k = 0; k < 10; k++) {
        unsigned eu = h2u(erh[k]), pu = h2u(prh[k]);
        part[base + k * 80 + l] = (eu & 0xFFFFu) | (pu << 16);
        if (isB) part[base + k * 80 + 64 + l] = (eu >> 16) | (pu & 0xFFFF0000u);
    }
}

// ---------------- K2: reduce NCG partials + edge density -> feat_t ch 64..95 ----------------
// grid (8 bands, 16 b), 256 threads
__launch_bounds__(256)
__global__ void density_kernel(const unsigned* __restrict__ part,
                               _Float16* __restrict__ feat_t) {
    __shared__ float E[14][84];
    __shared__ float Hs[14][84];
    __shared__ float Ps[10][80];
    int band = blockIdx.x, b = blockIdx.y, tid = threadIdx.x;
    int r0 = band * 10;
    if (tid < 56) { int rr = tid >> 2, c4 = tid & 3; E[rr][(c4 < 2) ? c4 : 80 + c4] = 0.f; }
    for (int idx = tid; idx < 14 * 80; idx += 256) {
        int rr = idx / 80, j = idx - rr * 80;
        int row = r0 - 2 + rr;
        float e = 0.f, p = 0.f;
        if (row >= 0 && row < 80) {
            size_t off = ((size_t)b * 80 + row) * 80 + j;
#pragma unroll 4
            for (int g = 0; g < NCG; g++) {
                h2 v = u2h(part[(size_t)g * (16 * 80 * 80) + off]);
                e += h2lo(v); p += h2hi(v);
            }
        }
        E[rr][2 + j] = e * (1.f / 256.f);
        if (rr >= 2 && rr < 12) Ps[rr - 2][j] = p * (1.f / 256.f);
    }
    __syncthreads();
    for (int idx = tid; idx < 14 * 80; idx += 256) {
        int rr = idx / 80, j = idx - rr * 80;
        Hs[rr][2 + j] = E[rr][j] + E[rr][j + 1] + E[rr][j + 2] + E[rr][j + 3] + E[rr][j + 4];
    }
    __syncthreads();
    for (int idx = tid; idx < 10 * 80; idx += 256) {
        int k = idx / 80, j = idx - k * 80;
        int rr = k + 2;
        float pool = Hs[rr - 2][2 + j] + Hs[rr - 1][2 + j] + Hs[rr][2 + j]
                   + Hs[rr + 1][2 + j] + Hs[rr + 2][2 + j];
        float ed = E[rr][2 + j] / (pool * 0.04f + 1e-6f);
        _Float16* fp = feat_t + ((size_t)(b * HWN) + (r0 + k) * 80 + j) * 96;
        f16x8 z8 = {};
        f16x8 f8 = {};
        f8[0] = (_Float16)ed; f8[1] = (_Float16)Ps[k][j];
        *reinterpret_cast<f16x8*>(fp + 64) = f8;
        *reinterpret_cast<f16x8*>(fp + 72) = z8;
        *reinterpret_cast<f16x8*>(fp + 80) = z8;
        *reinterpret_cast<f16x8*>(fp + 88) = z8;
    }
}

// ---------------- K3: proj via MFMA (unchanged) ----------------
__launch_bounds__(256)
__global__ void proj_kernel(const float* __restrict__ x,
                            const _Float16* __restrict__ apack,
                            const float* __restrict__ bias1,
                            _Float16* __restrict__ feat_t) {
    __shared__ __align__(16) unsigned char lds[64 * 512];
    int b = blockIdx.y, p0 = blockIdx.x * 64;
    int tid = threadIdx.x, w = tid >> 6, l = tid & 63;

#pragma unroll 4
    for (int i = 0; i < 16; i++) {
        int ch0 = i * 16 + w * 4;
        f16x4 v4;
#pragma unroll
        for (int q = 0; q < 4; q++)
            v4[q] = (_Float16)x[((size_t)(b * CC + ch0 + q)) * HWN + p0 + l];
        int byte = l * 512 + ((ch0 * 2) ^ ((l & 7) << 4));
        *reinterpret_cast<f16x4*>(lds + byte) = v4;
    }
    __syncthreads();

    const f16x8* Ap = reinterpret_cast<const f16x8*>(apack);
    f32x4 acc[4];
#pragma unroll
    for (int ct = 0; ct < 4; ct++) acc[ct] = (f32x4){0.f, 0.f, 0.f, 0.f};

    int kb = 16 * (l >> 4);
#pragma unroll 2
    for (int c = 0; c < 8; c++) {
        f16x8 a = Ap[(c * 4 + w) * 64 + l];
#pragma unroll
        for (int ct = 0; ct < 4; ct++) {
            int byte = (ct * 16 + (l & 15)) * 512 + ((c * 64 + kb) ^ ((l & 7) << 4));
            f16x8 bv = *reinterpret_cast<const f16x8*>(lds + byte);
            acc[ct] = __builtin_amdgcn_mfma_f32_16x16x32_f16(a, bv, acc[ct], 0, 0, 0);
        }
    }

    float b1v[4];
#pragma unroll
    for (int q = 0; q < 4; q++) b1v[q] = bias1[w * 16 + (l >> 4) * 4 + q];
#pragma unroll
    for (int ct = 0; ct < 4; ct++) {
        f16x4 o4;
#pragma unroll
        for (int q = 0; q < 4; q++) {
            float z = acc[ct][q] + b1v[q];
            o4[q] = (_Float16)(z / (1.f + expf(-z)));
        }
        size_t px = (size_t)(b * HWN) + p0 + ct * 16 + (l & 15);
        *reinterpret_cast<f16x4*>(feat_t + px * 96 + w * 16 + (l >> 4) * 4) = o4;
    }
}

// ---------------- K4: fuse via MFMA + epilogue + x*wgt (unchanged) ----------------
#define TROW 256
__launch_bounds__(256)
__global__ void fuse_kernel(const _Float16* __restrict__ feat_t,
                            const _Float16* __restrict__ apack,
                            const float* __restrict__ bias2,
                            const float* __restrict__ fuse2,
                            const float* __restrict__ x,
                            float* __restrict__ out) {
    __shared__ __align__(16) unsigned char tl[108 * TROW];
    __shared__ float R[4 * 4 * 4 * 16];
    __shared__ float wgtbuf[64];
    int b = blockIdx.y, t5 = blockIdx.x;
    int ti = t5 / 5, tj = t5 - ti * 5;
    int i0 = ti * 4, j0 = tj * 16;
    int tid = threadIdx.x, w = tid >> 6, l = tid & 63;

    for (int idx = tid; idx < 1296; idx += 256) {
        int hpx = idx / 12, g = idx - hpx * 12;
        int hr = hpx / 18, hc = hpx - hr * 18;
        int gi = i0 - 1 + hr, gj = j0 - 1 + hc;
        i32x4 val = {0, 0, 0, 0};
        if (gi >= 0 && gi < 80 && gj >= 0 && gj < 80) {
            val = *reinterpret_cast<const i32x4*>(
                feat_t + ((size_t)(b * HWN) + gi * 80 + gj) * 96 + g * 8);
        }
        *reinterpret_cast<i32x4*>(tl + hpx * TROW + ((g * 16) ^ ((hc & 7) << 4))) = val;
    }
    __syncthreads();

    const f16x8* Ap = reinterpret_cast<const f16x8*>(apack);
    f32x4 acc[4];
#pragma unroll
    for (int r = 0; r < 4; r++) acc[r] = (f32x4){0.f, 0.f, 0.f, 0.f};
    int kb = 16 * (l >> 4);

#pragma unroll 1
    for (int t = 0; t < 9; t++) {
        int dy = t / 3, dx = t - dy * 3;
        f16x8 a0 = Ap[((t * 3 + 0) * 4 + w) * 64 + l];
        f16x8 a1 = Ap[((t * 3 + 1) * 4 + w) * 64 + l];
        f16x8 a2 = Ap[((t * 3 + 2) * 4 + w) * 64 + l];
        int hc = (l & 15) + dx;
        int key = (hc & 7) << 4;
#pragma unroll
        for (int r = 0; r < 4; r++) {
            int base = ((r + dy) * 18 + hc) * TROW;
            f16x8 b0 = *reinterpret_cast<const f16x8*>(tl + base + ((0 + kb) ^ key));
            acc[r] = __builtin_amdgcn_mfma_f32_16x16x32_f16(a0, b0, acc[r], 0, 0, 0);
            f16x8 b1_ = *reinterpret_cast<const f16x8*>(tl + base + ((64 + kb) ^ key));
            acc[r] = __builtin_amdgcn_mfma_f32_16x16x32_f16(a1, b1_, acc[r], 0, 0, 0);
            f16x8 b2_ = *reinterpret_cast<const f16x8*>(tl + base + ((128 + kb) ^ key));
            acc[r] = __builtin_amdgcn_mfma_f32_16x16x32_f16(a2, b2_, acc[r], 0, 0, 0);
        }
    }

    float b2v[4], f2v[4];
#pragma unroll
    for (int q = 0; q < 4; q++) {
        int m = w * 16 + (l >> 4) * 4 + q;
        b2v[q] = bias2[m];
        f2v[q] = fuse2[m];
    }
#pragma unroll
    for (int r = 0; r < 4; r++) {
        float p = 0.f;
#pragma unroll
        for (int q = 0; q < 4; q++) {
            float z = acc[r][q] + b2v[q];
            p += f2v[q] * (z / (1.f + expf(-z)));
        }
        R[((w * 4 + r) * 4 + (l >> 4)) * 16 + (l & 15)] = p;
    }
    __syncthreads();
    if (tid < 64) {
        int r = tid >> 4, cc = tid & 15;
        float s = 0.f;
#pragma unroll
        for (int w2 = 0; w2 < 4; w2++)
#pragma unroll
            for (int g2 = 0; g2 < 4; g2++)
                s += R[((w2 * 4 + r) * 4 + g2) * 16 + cc];
        wgtbuf[tid] = 1.f / (1.f + expf(-s));
    }
    __syncthreads();

    int r = l >> 4, cc = l & 15;
    float wgt = wgtbuf[l];
    size_t base = (size_t)b * CC * HWN + (size_t)((i0 + r) * 80 + j0 + cc);
    const float* xp = x + base;
    float* op = out + base;
#pragma unroll 4
    for (int ch = w * 64; ch < w * 64 + 64; ch++) {
        op[(size_t)ch * HWN] = xp[(size_t)ch * HWN] * wgt;
    }
}

// ---------------- launch ----------------
extern "C" void kernel_launch(void* const* d_in, const int* in_sizes, int n_in,
                              void* d_out, int out_size, void* d_ws, size_t ws_size,
                              hipStream_t stream) {
    (void)in_sizes; (void)n_in; (void)out_size; (void)ws_size;
    const float* x       = (const float*)d_in[0];
    const float* proj_w  = (const float*)d_in[1];
    const float* bn1_g   = (const float*)d_in[2];
    const float* bn1_b   = (const float*)d_in[3];
    const float* bn1_m   = (const float*)d_in[4];
    const float* bn1_v   = (const float*)d_in[5];
    const float* fuse1_w = (const float*)d_in[6];
    const float* bn2_g   = (const float*)d_in[7];
    const float* bn2_b   = (const float*)d_in[8];
    const float* bn2_m   = (const float*)d_in[9];
    const float* bn2_v   = (const float*)d_in[10];
    const float* fuse2_w = (const float*)d_in[11];
    float* out = (float*)d_out;

    float* ws = (float*)d_ws;
    unsigned* part        = (unsigned*)ws;               // 64*16*6400 = 6,553,600 uints
    _Float16* feat_t      = (_Float16*)(ws + 6553600);   // 16*6400*96 f16 = 4,915,200 f
    _Float16* apack_proj  = (_Float16*)(ws + 11468800);  // 16384 f16
    _Float16* apack_fuse  = (_Float16*)(ws + 11476992);  // 55296 f16
    float*    bias1       = ws + 11504640;
    float*    bias2       = ws + 11504704;

    prep_kernel<<<288, 256, 0, stream>>>(proj_w, bn1_g, bn1_b, bn1_m, bn1_v,
                                         fuse1_w, bn2_g, bn2_b, bn2_m, bn2_v,
                                         apack_proj, apack_fuse, bias1, bias2);
    edge_period_kernel<<<dim3(NCG, 16), 512, 0, stream>>>(x, part);
    density_kernel<<<dim3(8, 16), 256, 0, stream>>>(part, feat_t);
    proj_kernel<<<dim3(100, 16), 256, 0, stream>>>(x, apack_proj, bias1, feat_t);
    fuse_kernel<<<dim3(100, 16), 256, 0, stream>>>(feat_t, apack_fuse,
                                                   bias2, fuse2_w, x, out);
}

// Round 15
// 526.622 us; speedup vs baseline: 1.2403x; 1.2403x over previous
//
#include <hip/hip_runtime.h>
#include <hip/hip_bf16.h>
#include <math.h>

#define HWN 6400
#define CC 256
#define MIDN 64
#define NCG 64   // channel groups for edge/period pass (4 ch each)

typedef _Float16 f16x8 __attribute__((ext_vector_type(8)));
typedef _Float16 f16x4 __attribute__((ext_vector_type(4)));
typedef _Float16 h2    __attribute__((ext_vector_type(2)));
typedef float    f32x4 __attribute__((ext_vector_type(4)));
typedef int      i32x4 __attribute__((ext_vector_type(4)));

__device__ __forceinline__ h2 pk2(float a, float b) {
    return __builtin_bit_cast(h2, __builtin_amdgcn_cvt_pkrtz(a, b));
}
__device__ __forceinline__ float h2lo(h2 v) { return (float)v[0]; }
__device__ __forceinline__ float h2hi(h2 v) { return (float)v[1]; }
__device__ __forceinline__ unsigned h2u(h2 v) { return __builtin_bit_cast(unsigned, v); }
__device__ __forceinline__ h2 u2h(unsigned u) { return __builtin_bit_cast(h2, u); }
__device__ __forceinline__ float vsqrtf_(float x) { float r; asm("v_sqrt_f32 %0, %1" : "=v"(r) : "v"(x)); return r; }

// ---------------- K0: fold BN, pack MFMA A-fragments (fp16) ----------------
__global__ void prep_kernel(const float* __restrict__ proj_w,
                            const float* __restrict__ g1, const float* __restrict__ b1,
                            const float* __restrict__ m1, const float* __restrict__ v1,
                            const float* __restrict__ f1w,
                            const float* __restrict__ g2, const float* __restrict__ b2,
                            const float* __restrict__ m2, const float* __restrict__ v2,
                            _Float16* __restrict__ apack_proj,
                            _Float16* __restrict__ apack_fuse,
                            float* __restrict__ bias1, float* __restrict__ bias2) {
    int gid = blockIdx.x * blockDim.x + threadIdx.x;
    int stride = gridDim.x * blockDim.x;
    if (gid < MIDN) {
        float s1 = g1[gid] * rsqrtf(v1[gid] + 1e-5f);
        bias1[gid] = b1[gid] - m1[gid] * s1;
        float s2 = g2[gid] * rsqrtf(v2[gid] + 1e-5f);
        bias2[gid] = b2[gid] - m2[gid] * s2;
    }
    for (int i = gid; i < 8 * 4 * 64 * 8; i += stride) {
        int j = i & 7, lane = (i >> 3) & 63, w = (i >> 9) & 3, c = i >> 11;
        int m = w * 16 + (lane & 15);
        int ch = c * 32 + (lane >> 4) * 8 + j;
        float s1 = g1[m] * rsqrtf(v1[m] + 1e-5f);
        apack_proj[i] = (_Float16)(proj_w[m * CC + ch] * s1);
    }
    for (int i = gid; i < 9 * 3 * 4 * 64 * 8; i += stride) {
        int j = i & 7, lane = (i >> 3) & 63, w = (i >> 9) & 3;
        int tc = i >> 11; int c = tc % 3, t = tc / 3;
        int m = w * 16 + (lane & 15);
        int ch = c * 32 + (lane >> 4) * 8 + j;
        float s2 = g2[m] * rsqrtf(v2[m] + 1e-5f);
        float v = 0.f;
        if (ch < 66) v = f1w[(m * 66 + ch) * 9 + t] * s2;
        apack_fuse[i] = (_Float16)v;
    }
}

// ---------------- K1: edge + period, wave-band column-march ----------------
// grid (NCG=64 cg, 16 b), 512 thr = 8 waves; wave w owns rows [10w,10w+10),
// lane l owns cols {l, 64+l(l<16)}; 4 channels/block. No __syncthreads.
// wb volatile (cross-lane same-wave LDS dep; volatile order + in-order DS
// pipe). Channel accumulation in per-wave LDS acc (h2 {er,pr}) -- removes
// the 20-reg accumulator arrays so VGPR fits under the 3-blocks/CU cap (42)
// without spilling. launch_bounds(512,6) => 3 blocks/CU = 24 waves/CU.
__launch_bounds__(512, 6)
__global__ void edge_period_kernel(const float* __restrict__ x,
                                   unsigned* __restrict__ part) {
    __shared__ unsigned wb[8][88];
    __shared__ unsigned accv[8 * 10 * 80];   // per-wave {er,pr} h2 accumulators
    volatile unsigned (*wbv)[88] = wb;
    int tid = threadIdx.x;
    int w = tid >> 6, l = tid & 63;
    int b = blockIdx.y, cg = blockIdx.x;
    int row0 = w * 10;
    int im1 = (l + 63) & 63, ip1 = (l + 1) & 63;
    bool is0 = (l == 0), is63 = (l == 63), isB = (l < 16);

    if (l < 4) wbv[w][(l < 2) ? l : 80 + l] = 0u;   // zero pad cols idx 0,1,82,83
    // zero this wave's acc slice (wave-private; same-wave DS in-order)
    for (int i = l; i < 800; i += 64) accv[w * 800 + i] = 0u;

    // column resize weights (0.5 of Haar folded in)
    float cwA = (l <= 0) ? 1.f : ((l >= 79) ? 0.f : (0.99375f - 0.0125f * (float)l));
    int cB = 64 + l;
    float cwB = (cB >= 79) ? 0.f : (0.99375f - 0.0125f * (float)cB);
    h2 v_pk = pk2(0.5f * cwA, 0.5f * cwB);
    h2 u_pk = pk2(0.5f * (1.f - cwA), 0.5f * (1.f - cwB));

    h2 ering[2];
    ering[0] = u2h(0u); ering[1] = u2h(0u);

#pragma unroll 1
    for (int ch = 0; ch < 4; ch++) {
        const float* xch = x + ((size_t)(b * CC + cg * 4 + ch)) * HWN;
        auto ldtrip = [&](int rr, h2& t0, h2& t1, h2& t2) {
            float a = 0.f, bb = 0.f;
            if (rr >= 0 && rr < 80) {
                a = xch[rr * 80 + l];
                if (isB) bb = xch[rr * 80 + 64 + l];
            }
            h2 xc = pk2(a, bb);
            int xi = __builtin_bit_cast(int, xc);
            unsigned um = (unsigned)__shfl(xi, im1);
            unsigned up = (unsigned)__shfl(xi, ip1);
            um = is0 ? ((um & 0xFFFFu) << 16) : um;   // lane0: {0, col63}
            up = is63 ? (up >> 16) : up;              // lane63: {col64, 0}
            t0 = u2h(um); t1 = xc; t2 = u2h(up);
        };
        h2 xm1_0, xm1_1, xm1_2, x0_0, x0_1, x0_2, xp1_0, xp1_1, xp1_2;
        ldtrip(row0 - 3, xm1_0, xm1_1, xm1_2);
        ldtrip(row0 - 2, x0_0, x0_1, x0_2);
        // seam init: lhc_p/hlc_p = column-resized haar at row pair (row0-3, row0-2)
        h2 lhc_p, hlc_p;
        {
            h2 sa = xm1_0 + x0_0, sb = xm1_1 + x0_1, sc2 = xm1_2 + x0_2;
            h2 da = xm1_0 - x0_0, db = xm1_1 - x0_1, dc = xm1_2 - x0_2;
            lhc_p = u_pk * (sa - sb) + v_pk * (sb - sc2);
            hlc_p = u_pk * (da + db) + v_pk * (db + dc);
        }
        h2 ringA[5], ringB[5], ringS[5];
#pragma unroll
        for (int s = 0; s < 14; s++) {
            int r = row0 - 2 + s;
            ldtrip(r + 1, xp1_0, xp1_1, xp1_2);
            // Sobel (own rows only; r in [row0,row0+10) for s in [2,12))
            h2 er_new = u2h(0u);
            if (s >= 2 && s < 12) {
                h2 gx = (xm1_2 - xm1_0) + (x0_2 - x0_0) + (x0_2 - x0_0) + (xp1_2 - xp1_0);
                h2 gy = (xp1_0 - xm1_0) + (xp1_1 - xm1_1) + (xp1_1 - xm1_1) + (xp1_2 - xm1_2);
                h2 g2v = gx * gx + gy * gy;
                er_new = pk2(vsqrtf_(h2lo(g2v)) * 0.125f, vsqrtf_(h2hi(g2v)) * 0.125f);
            }
            // Haar row pair (r, r+1) -> column-resized lh/hl, then row-resize
            h2 sa = x0_0 + xp1_0, sb = x0_1 + xp1_1, sc2 = x0_2 + xp1_2;
            h2 da = x0_0 - xp1_0, db = x0_1 - xp1_1, dc = x0_2 - xp1_2;
            h2 lhc = u_pk * (sa - sb) + v_pk * (sb - sc2);
            h2 hlc = u_pk * (da + db) + v_pk * (db + dc);
            float cw = (r <= 0) ? 1.f : ((r >= 79) ? 0.f : (0.99375f - 0.0125f * (float)r));
            h2 cwp = pk2(cw, cw), pwp = pk2(1.f - cw, 1.f - cw);
            h2 lhr = pwp * lhc_p + cwp * lhc;
            h2 hlr = pwp * hlc_p + cwp * hlc;
            lhc_p = lhc; hlc_p = hlc;
            unsigned lu = h2u(lhr), hu = h2u(hlr);
            unsigned fA = (lu & 0xFFFFu) | (hu << 16);           // {lh,hl} col l
            unsigned fB = (lu >> 16) | (hu & 0xFFFF0000u);       // {lh,hl} col 64+l
            bool fv = (r >= 0) && (r < 80);
            if (!fv) { fA = 0u; fB = 0u; }
            // horizontal 5-sum via per-wave LDS row (volatile keeps order)
            wbv[w][2 + l] = fA;
            if (isB) wbv[w][66 + l] = fB;
            unsigned am2 = wbv[w][l], am1 = wbv[w][l + 1], ap1 = wbv[w][l + 3], ap2 = wbv[w][l + 4];
            unsigned bm2 = 0, bm1 = 0, bp1 = 0, bp2 = 0;
            if (isB) { bm2 = wbv[w][64 + l]; bm1 = wbv[w][65 + l]; bp1 = wbv[w][67 + l]; bp2 = wbv[w][68 + l]; }
            h2 fAh = u2h(fA), fBh = u2h(fB);
            h2 n0 = u2h(am2), n1 = u2h(am1), n2 = u2h(ap1), n3 = u2h(ap2);
            h2 hA = fAh + n0 + n1 + n2 + n3;
            h2 qa = fAh * fAh + n0 * n0 + n1 * n1 + n2 * n2 + n3 * n3;
            float s2A = h2lo(qa) + h2hi(qa);
            h2 m0 = u2h(bm2), m1 = u2h(bm1), m2 = u2h(bp1), m3 = u2h(bp2);
            h2 hB = fBh + m0 + m1 + m2 + m3;
            h2 qb = fBh * fBh + m0 * m0 + m1 * m1 + m2 * m2 + m3 * m3;
            float s2B = h2lo(qb) + h2hi(qb);
            ringA[s % 5] = hA; ringB[s % 5] = hB;
            ringS[s % 5] = pk2(s2A, s2B);
            // vertical 5-sum + variance + emit row s-4 into LDS acc
            if (s >= 4) {
                h2 SA = ringA[0] + ringA[1] + ringA[2] + ringA[3] + ringA[4];
                h2 SB = ringB[0] + ringB[1] + ringB[2] + ringB[3] + ringB[4];
                h2 S2 = ringS[0] + ringS[1] + ringS[2] + ringS[3] + ringS[4];
                float SLA = h2lo(SA), SHA = h2hi(SA);
                float SLB = h2lo(SB), SHB = h2hi(SB);
                float vA = 0.04f * h2lo(S2) - 0.0016f * (SLA * SLA + SHA * SHA);
                float vB = 0.04f * h2hi(S2) - 0.0016f * (SLB * SLB + SHB * SHB);
                vA = fmaxf(vA, 0.f) + 1e-6f;
                vB = fmaxf(vB, 0.f) + 1e-6f;
                h2 old_er = ering[s & 1];           // er for row s-4 (stored at s-2)
                int aidx = w * 800 + (s - 4) * 80;
                h2 aA = u2h(accv[aidx + l]) + pk2(h2lo(old_er), vsqrtf_(vA));
                accv[aidx + l] = h2u(aA);
                if (isB) {
                    h2 aB = u2h(accv[aidx + 64 + l]) + pk2(h2hi(old_er), vsqrtf_(vB));
                    accv[aidx + 64 + l] = h2u(aB);
                }
            }
            if (s >= 2 && s < 12) ering[s & 1] = er_new;   // after old_er consumed
            xm1_0 = x0_0; xm1_1 = x0_1; xm1_2 = x0_2;
            x0_0 = xp1_0; x0_1 = xp1_1; x0_2 = xp1_2;
        }
    }
    size_t base = ((size_t)(cg * 16 + b) * 80 + row0) * 80;
#pragma unroll
    for (int k = 0; k < 10; k++) {
        part[base + k * 80 + l] = accv[w * 800 + k * 80 + l];
        if (isB) part[base + k * 80 + 64 + l] = accv[w * 800 + k * 80 + 64 + l];
    }
}

// ---------------- K2: reduce NCG partials + edge density -> feat_t ch 64..95 ----------------
// grid (8 bands, 16 b), 256 threads
__launch_bounds__(256)
__global__ void density_kernel(const unsigned* __restrict__ part,
                               _Float16* __restrict__ feat_t) {
    __shared__ float E[14][84];
    __shared__ float Hs[14][84];
    __shared__ float Ps[10][80];
    int band = blockIdx.x, b = blockIdx.y, tid = threadIdx.x;
    int r0 = band * 10;
    if (tid < 56) { int rr = tid >> 2, c4 = tid & 3; E[rr][(c4 < 2) ? c4 : 80 + c4] = 0.f; }
    for (int idx = tid; idx < 14 * 80; idx += 256) {
        int rr = idx / 80, j = idx - rr * 80;
        int row = r0 - 2 + rr;
        float e = 0.f, p = 0.f;
        if (row >= 0 && row < 80) {
            size_t off = ((size_t)b * 80 + row) * 80 + j;
#pragma unroll 4
            for (int g = 0; g < NCG; g++) {
                h2 v = u2h(part[(size_t)g * (16 * 80 * 80) + off]);
                e += h2lo(v); p += h2hi(v);
            }
        }
        E[rr][2 + j] = e * (1.f / 256.f);
        if (rr >= 2 && rr < 12) Ps[rr - 2][j] = p * (1.f / 256.f);
    }
    __syncthreads();
    for (int idx = tid; idx < 14 * 80; idx += 256) {
        int rr = idx / 80, j = idx - rr * 80;
        Hs[rr][2 + j] = E[rr][j] + E[rr][j + 1] + E[rr][j + 2] + E[rr][j + 3] + E[rr][j + 4];
    }
    __syncthreads();
    for (int idx = tid; idx < 10 * 80; idx += 256) {
        int k = idx / 80, j = idx - k * 80;
        int rr = k + 2;
        float pool = Hs[rr - 2][2 + j] + Hs[rr - 1][2 + j] + Hs[rr][2 + j]
                   + Hs[rr + 1][2 + j] + Hs[rr + 2][2 + j];
        float ed = E[rr][2 + j] / (pool * 0.04f + 1e-6f);
        _Float16* fp = feat_t + ((size_t)(b * HWN) + (r0 + k) * 80 + j) * 96;
        f16x8 z8 = {};
        f16x8 f8 = {};
        f8[0] = (_Float16)ed; f8[1] = (_Float16)Ps[k][j];
        *reinterpret_cast<f16x8*>(fp + 64) = f8;
        *reinterpret_cast<f16x8*>(fp + 72) = z8;
        *reinterpret_cast<f16x8*>(fp + 80) = z8;
        *reinterpret_cast<f16x8*>(fp + 88) = z8;
    }
}

// ---------------- K3: proj via MFMA (unchanged) ----------------
__launch_bounds__(256)
__global__ void proj_kernel(const float* __restrict__ x,
                            const _Float16* __restrict__ apack,
                            const float* __restrict__ bias1,
                            _Float16* __restrict__ feat_t) {
    __shared__ __align__(16) unsigned char lds[64 * 512];
    int b = blockIdx.y, p0 = blockIdx.x * 64;
    int tid = threadIdx.x, w = tid >> 6, l = tid & 63;

#pragma unroll 4
    for (int i = 0; i < 16; i++) {
        int ch0 = i * 16 + w * 4;
        f16x4 v4;
#pragma unroll
        for (int q = 0; q < 4; q++)
            v4[q] = (_Float16)x[((size_t)(b * CC + ch0 + q)) * HWN + p0 + l];
        int byte = l * 512 + ((ch0 * 2) ^ ((l & 7) << 4));
        *reinterpret_cast<f16x4*>(lds + byte) = v4;
    }
    __syncthreads();

    const f16x8* Ap = reinterpret_cast<const f16x8*>(apack);
    f32x4 acc[4];
#pragma unroll
    for (int ct = 0; ct < 4; ct++) acc[ct] = (f32x4){0.f, 0.f, 0.f, 0.f};

    int kb = 16 * (l >> 4);
#pragma unroll 2
    for (int c = 0; c < 8; c++) {
        f16x8 a = Ap[(c * 4 + w) * 64 + l];
#pragma unroll
        for (int ct = 0; ct < 4; ct++) {
            int byte = (ct * 16 + (l & 15)) * 512 + ((c * 64 + kb) ^ ((l & 7) << 4));
            f16x8 bv = *reinterpret_cast<const f16x8*>(lds + byte);
            acc[ct] = __builtin_amdgcn_mfma_f32_16x16x32_f16(a, bv, acc[ct], 0, 0, 0);
        }
    }

    float b1v[4];
#pragma unroll
    for (int q = 0; q < 4; q++) b1v[q] = bias1[w * 16 + (l >> 4) * 4 + q];
#pragma unroll
    for (int ct = 0; ct < 4; ct++) {
        f16x4 o4;
#pragma unroll
        for (int q = 0; q < 4; q++) {
            float z = acc[ct][q] + b1v[q];
            o4[q] = (_Float16)(z / (1.f + expf(-z)));
        }
        size_t px = (size_t)(b * HWN) + p0 + ct * 16 + (l & 15);
        *reinterpret_cast<f16x4*>(feat_t + px * 96 + w * 16 + (l >> 4) * 4) = o4;
    }
}

// ---------------- K4: fuse via MFMA + epilogue + x*wgt (unchanged) ----------------
#define TROW 256
__launch_bounds__(256)
__global__ void fuse_kernel(const _Float16* __restrict__ feat_t,
                            const _Float16* __restrict__ apack,
                            const float* __restrict__ bias2,
                            const float* __restrict__ fuse2,
                            const float* __restrict__ x,
                            float* __restrict__ out) {
    __shared__ __align__(16) unsigned char tl[108 * TROW];
    __shared__ float R[4 * 4 * 4 * 16];
    __shared__ float wgtbuf[64];
    int b = blockIdx.y, t5 = blockIdx.x;
    int ti = t5 / 5, tj = t5 - ti * 5;
    int i0 = ti * 4, j0 = tj * 16;
    int tid = threadIdx.x, w = tid >> 6, l = tid & 63;

    for (int idx = tid; idx < 1296; idx += 256) {
        int hpx = idx / 12, g = idx - hpx * 12;
        int hr = hpx / 18, hc = hpx - hr * 18;
        int gi = i0 - 1 + hr, gj = j0 - 1 + hc;
        i32x4 val = {0, 0, 0, 0};
        if (gi >= 0 && gi < 80 && gj >= 0 && gj < 80) {
            val = *reinterpret_cast<const i32x4*>(
                feat_t + ((size_t)(b * HWN) + gi * 80 + gj) * 96 + g * 8);
        }
        *reinterpret_cast<i32x4*>(tl + hpx * TROW + ((g * 16) ^ ((hc & 7) << 4))) = val;
    }
    __syncthreads();

    const f16x8* Ap = reinterpret_cast<const f16x8*>(apack);
    f32x4 acc[4];
#pragma unroll
    for (int r = 0; r < 4; r++) acc[r] = (f32x4){0.f, 0.f, 0.f, 0.f};
    int kb = 16 * (l >> 4);

#pragma unroll 1
    for (int t = 0; t < 9; t++) {
        int dy = t / 3, dx = t - dy * 3;
        f16x8 a0 = Ap[((t * 3 + 0) * 4 + w) * 64 + l];
        f16x8 a1 = Ap[((t * 3 + 1) * 4 + w) * 64 + l];
        f16x8 a2 = Ap[((t * 3 + 2) * 4 + w) * 64 + l];
        int hc = (l & 15) + dx;
        int key = (hc & 7) << 4;
#pragma unroll
        for (int r = 0; r < 4; r++) {
            int base = ((r + dy) * 18 + hc) * TROW;
            f16x8 b0 = *reinterpret_cast<const f16x8*>(tl + base + ((0 + kb) ^ key));
            acc[r] = __builtin_amdgcn_mfma_f32_16x16x32_f16(a0, b0, acc[r], 0, 0, 0);
            f16x8 b1_ = *reinterpret_cast<const f16x8*>(tl + base + ((64 + kb) ^ key));
            acc[r] = __builtin_amdgcn_mfma_f32_16x16x32_f16(a1, b1_, acc[r], 0, 0, 0);
            f16x8 b2_ = *reinterpret_cast<const f16x8*>(tl + base + ((128 + kb) ^ key));
            acc[r] = __builtin_amdgcn_mfma_f32_16x16x32_f16(a2, b2_, acc[r], 0, 0, 0);
        }
    }

    float b2v[4], f2v[4];
#pragma unroll
    for (int q = 0; q < 4; q++) {
        int m = w * 16 + (l >> 4) * 4 + q;
        b2v[q] = bias2[m];
        f2v[q] = fuse2[m];
    }
#pragma unroll
    for (int r = 0; r < 4; r++) {
        float p = 0.f;
#pragma unroll
        for (int q = 0; q < 4; q++) {
            float z = acc[r][q] + b2v[q];
            p += f2v[q] * (z / (1.f + expf(-z)));
        }
        R[((w * 4 + r) * 4 + (l >> 4)) * 16 + (l & 15)] = p;
    }
    __syncthreads();
    if (tid < 64) {
        int r = tid >> 4, cc = tid & 15;
        float s = 0.f;
#pragma unroll
        for (int w2 = 0; w2 < 4; w2++)
#pragma unroll
            for (int g2 = 0; g2 < 4; g2++)
                s += R[((w2 * 4 + r) * 4 + g2) * 16 + cc];
        wgtbuf[tid] = 1.f / (1.f + expf(-s));
    }
    __syncthreads();

    int r = l >> 4, cc = l & 15;
    float wgt = wgtbuf[l];
    size_t base = (size_t)b * CC * HWN + (size_t)((i0 + r) * 80 + j0 + cc);
    const float* xp = x + base;
    float* op = out + base;
#pragma unroll 4
    for (int ch = w * 64; ch < w * 64 + 64; ch++) {
        op[(size_t)ch * HWN] = xp[(size_t)ch * HWN] * wgt;
    }
}

// ---------------- launch ----------------
extern "C" void kernel_launch(void* const* d_in, const int* in_sizes, int n_in,
                              void* d_out, int out_size, void* d_ws, size_t ws_size,
                              hipStream_t stream) {
    (void)in_sizes; (void)n_in; (void)out_size; (void)ws_size;
    const float* x       = (const float*)d_in[0];
    const float* proj_w  = (const float*)d_in[1];
    const float* bn1_g   = (const float*)d_in[2];
    const float* bn1_b   = (const float*)d_in[3];
    const float* bn1_m   = (const float*)d_in[4];
    const float* bn1_v   = (const float*)d_in[5];
    const float* fuse1_w = (const float*)d_in[6];
    const float* bn2_g   = (const float*)d_in[7];
    const float* bn2_b   = (const float*)d_in[8];
    const float* bn2_m   = (const float*)d_in[9];
    const float* bn2_v   = (const float*)d_in[10];
    const float* fuse2_w = (const float*)d_in[11];
    float* out = (float*)d_out;

    float* ws = (float*)d_ws;
    unsigned* part        = (unsigned*)ws;               // 64*16*6400 = 6,553,600 uints
    _Float16* feat_t      = (_Float16*)(ws + 6553600);   // 16*6400*96 f16 = 4,915,200 f
    _Float16* apack_proj  = (_Float16*)(ws + 11468800);  // 16384 f16
    _Float16* apack_fuse  = (_Float16*)(ws + 11476992);  // 55296 f16
    float*    bias1       = ws + 11504640;
    float*    bias2       = ws + 11504704;

    prep_kernel<<<288, 256, 0, stream>>>(proj_w, bn1_g, bn1_b, bn1_m, bn1_v,
                                         fuse1_w, bn2_g, bn2_b, bn2_m, bn2_v,
                                         apack_proj, apack_fuse, bias1, bias2);
    edge_period_kernel<<<dim3(NCG, 16), 512, 0, stream>>>(x, part);
    density_kernel<<<dim3(8, 16), 256, 0, stream>>>(part, feat_t);
    proj_kernel<<<dim3(100, 16), 256, 0, stream>>>(x, apack_proj, bias1, feat_t);
    fuse_kernel<<<dim3(100, 16), 256, 0, stream>>>(feat_t, apack_fuse,
                                                   bias2, fuse2_w, x, out);
}

// Round 16
// 265.053 us; speedup vs baseline: 2.4644x; 1.9869x over previous
//
#include <hip/hip_runtime.h>
#include <hip/hip_bf16.h>
#include <math.h>

#define HWN 6400
#define CC 256
#define MIDN 64
#define NCG 64   // channel groups for edge/period pass (4 ch each)

typedef _Float16 f16x8 __attribute__((ext_vector_type(8)));
typedef _Float16 f16x4 __attribute__((ext_vector_type(4)));
typedef _Float16 h2    __attribute__((ext_vector_type(2)));
typedef float    f32x4 __attribute__((ext_vector_type(4)));
typedef int      i32x4 __attribute__((ext_vector_type(4)));

__device__ __forceinline__ h2 pk2(float a, float b) {
    return __builtin_bit_cast(h2, __builtin_amdgcn_cvt_pkrtz(a, b));
}
__device__ __forceinline__ float h2lo(h2 v) { return (float)v[0]; }
__device__ __forceinline__ float h2hi(h2 v) { return (float)v[1]; }
__device__ __forceinline__ unsigned h2u(h2 v) { return __builtin_bit_cast(unsigned, v); }
__device__ __forceinline__ h2 u2h(unsigned u) { return __builtin_bit_cast(h2, u); }
__device__ __forceinline__ float vsqrtf_(float x) { float r; asm("v_sqrt_f32 %0, %1" : "=v"(r) : "v"(x)); return r; }

// ---------------- K0: fold BN, pack MFMA A-fragments (fp16) ----------------
__global__ void prep_kernel(const float* __restrict__ proj_w,
                            const float* __restrict__ g1, const float* __restrict__ b1,
                            const float* __restrict__ m1, const float* __restrict__ v1,
                            const float* __restrict__ f1w,
                            const float* __restrict__ g2, const float* __restrict__ b2,
                            const float* __restrict__ m2, const float* __restrict__ v2,
                            _Float16* __restrict__ apack_proj,
                            _Float16* __restrict__ apack_fuse,
                            float* __restrict__ bias1, float* __restrict__ bias2) {
    int gid = blockIdx.x * blockDim.x + threadIdx.x;
    int stride = gridDim.x * blockDim.x;
    if (gid < MIDN) {
        float s1 = g1[gid] * rsqrtf(v1[gid] + 1e-5f);
        bias1[gid] = b1[gid] - m1[gid] * s1;
        float s2 = g2[gid] * rsqrtf(v2[gid] + 1e-5f);
        bias2[gid] = b2[gid] - m2[gid] * s2;
    }
    for (int i = gid; i < 8 * 4 * 64 * 8; i += stride) {
        int j = i & 7, lane = (i >> 3) & 63, w = (i >> 9) & 3, c = i >> 11;
        int m = w * 16 + (lane & 15);
        int ch = c * 32 + (lane >> 4) * 8 + j;
        float s1 = g1[m] * rsqrtf(v1[m] + 1e-5f);
        apack_proj[i] = (_Float16)(proj_w[m * CC + ch] * s1);
    }
    for (int i = gid; i < 9 * 3 * 4 * 64 * 8; i += stride) {
        int j = i & 7, lane = (i >> 3) & 63, w = (i >> 9) & 3;
        int tc = i >> 11; int c = tc % 3, t = tc / 3;
        int m = w * 16 + (lane & 15);
        int ch = c * 32 + (lane >> 4) * 8 + j;
        float s2 = g2[m] * rsqrtf(v2[m] + 1e-5f);
        float v = 0.f;
        if (ch < 66) v = f1w[(m * 66 + ch) * 9 + t] * s2;
        apack_fuse[i] = (_Float16)v;
    }
}

// ---------------- K1: edge + period, wave-band column-march, prefetched ----------------
// grid (NCG=64 cg, 16 b), 512 thr = 8 waves; wave w owns rows [10w,10w+10),
// lane l owns cols {l, 64+l(l<16)}; 4 channels/block. No __syncthreads;
// wb volatile (order preserved; per-wave DS queue in-order), no fences so
// loads pipeline. h2-packed accumulators AND h2 ringS so the natural VGPR
// demand lands ~50 (no spill) under launch_bounds(512,4) cap of 64 --
// R13 spilled ~150MB at f32 accums; R14's forced cap 32 spilled worse.
__launch_bounds__(512, 4)
__global__ void edge_period_kernel(const float* __restrict__ x,
                                   unsigned* __restrict__ part) {
    __shared__ unsigned wb[8][88];
    volatile unsigned (*wbv)[88] = wb;
    int tid = threadIdx.x;
    int w = tid >> 6, l = tid & 63;
    int b = blockIdx.y, cg = blockIdx.x;
    int row0 = w * 10;
    int im1 = (l + 63) & 63, ip1 = (l + 1) & 63;
    bool is0 = (l == 0), is63 = (l == 63), isB = (l < 16);

    if (l < 4) wbv[w][(l < 2) ? l : 80 + l] = 0u;   // zero pad cols idx 0,1,82,83

    // column resize weights (0.5 of Haar folded in)
    float cwA = (l <= 0) ? 1.f : ((l >= 79) ? 0.f : (0.99375f - 0.0125f * (float)l));
    int cB = 64 + l;
    float cwB = (cB >= 79) ? 0.f : (0.99375f - 0.0125f * (float)cB);
    h2 v_pk = pk2(0.5f * cwA, 0.5f * cwB);
    h2 u_pk = pk2(0.5f * (1.f - cwA), 0.5f * (1.f - cwB));

    h2 erh[10], prh[10];
#pragma unroll
    for (int k = 0; k < 10; k++) { erh[k] = u2h(0u); prh[k] = u2h(0u); }

#pragma unroll 1
    for (int ch = 0; ch < 4; ch++) {
        const float* xch = x + ((size_t)(b * CC + cg * 4 + ch)) * HWN;
        auto rawload = [&](int rr, float& a, float& bb) {
            a = 0.f; bb = 0.f;
            if (rr >= 0 && rr < 80) {
                a = xch[rr * 80 + l];
                if (isB) bb = xch[rr * 80 + 64 + l];
            }
        };
        auto mktrip = [&](float a, float bb, h2& t0, h2& t1, h2& t2) {
            h2 xc = pk2(a, bb);
            int xi = __builtin_bit_cast(int, xc);
            unsigned um = (unsigned)__shfl(xi, im1);
            unsigned up = (unsigned)__shfl(xi, ip1);
            um = is0 ? ((um & 0xFFFFu) << 16) : um;   // lane0: {0, col63}
            up = is63 ? (up >> 16) : up;              // lane63: {col64, 0}
            t0 = u2h(um); t1 = xc; t2 = u2h(up);
        };
        h2 xm1_0, xm1_1, xm1_2, x0_0, x0_1, x0_2, xp1_0, xp1_1, xp1_2;
        float ta, tb, ra, rb, na, nb;
        rawload(row0 - 3, ta, tb);
        rawload(row0 - 2, ra, rb);
        mktrip(ta, tb, xm1_0, xm1_1, xm1_2);
        mktrip(ra, rb, x0_0, x0_1, x0_2);
        rawload(row0 - 1, ra, rb);          // raw row for s=0's xp1
        // seam init: lhc_p/hlc_p = column-resized haar at row pair (row0-3, row0-2)
        h2 lhc_p, hlc_p;
        {
            h2 sa = xm1_0 + x0_0, sb = xm1_1 + x0_1, sc2 = xm1_2 + x0_2;
            h2 da = xm1_0 - x0_0, db = xm1_1 - x0_1, dc = xm1_2 - x0_2;
            lhc_p = u_pk * (sa - sb) + v_pk * (sb - sc2);
            hlc_p = u_pk * (da + db) + v_pk * (db + dc);
        }
        h2 ringA[5], ringB[5], ringS[5];
#pragma unroll
        for (int s = 0; s < 14; s++) {
            int r = row0 - 2 + s;
            // issue next raw row load early (consumed next iteration)
            if (s < 13) rawload(row0 + s, na, nb);
            // convert + shuffle the row loaded last iteration (full iter of slack)
            mktrip(ra, rb, xp1_0, xp1_1, xp1_2);
            // Sobel (own rows only; r in [row0,row0+10) guaranteed for s in [2,12))
            if (s >= 2 && s < 12) {
                h2 gx = (xm1_2 - xm1_0) + (x0_2 - x0_0) + (x0_2 - x0_0) + (xp1_2 - xp1_0);
                h2 gy = (xp1_0 - xm1_0) + (xp1_1 - xm1_1) + (xp1_1 - xm1_1) + (xp1_2 - xm1_2);
                h2 g2v = gx * gx + gy * gy;
                erh[s - 2] += pk2(vsqrtf_(h2lo(g2v)) * 0.125f, vsqrtf_(h2hi(g2v)) * 0.125f);
            }
            // Haar row pair (r, r+1) -> column-resized lh/hl, then row-resize
            h2 sa = x0_0 + xp1_0, sb = x0_1 + xp1_1, sc2 = x0_2 + xp1_2;
            h2 da = x0_0 - xp1_0, db = x0_1 - xp1_1, dc = x0_2 - xp1_2;
            h2 lhc = u_pk * (sa - sb) + v_pk * (sb - sc2);
            h2 hlc = u_pk * (da + db) + v_pk * (db + dc);
            float cw = (r <= 0) ? 1.f : ((r >= 79) ? 0.f : (0.99375f - 0.0125f * (float)r));
            h2 cwp = pk2(cw, cw), pwp = pk2(1.f - cw, 1.f - cw);
            h2 lhr = pwp * lhc_p + cwp * lhc;
            h2 hlr = pwp * hlc_p + cwp * hlc;
            lhc_p = lhc; hlc_p = hlc;
            unsigned lu = h2u(lhr), hu = h2u(hlr);
            unsigned fA = (lu & 0xFFFFu) | (hu << 16);           // {lh,hl} col l
            unsigned fB = (lu >> 16) | (hu & 0xFFFF0000u);       // {lh,hl} col 64+l
            bool fv = (r >= 0) && (r < 80);
            if (!fv) { fA = 0u; fB = 0u; }
            // horizontal 5-sum via per-wave LDS row (volatile keeps write->read
            // order; same-wave DS pipe executes in order)
            wbv[w][2 + l] = fA;
            if (isB) wbv[w][66 + l] = fB;
            unsigned am2 = wbv[w][l], am1 = wbv[w][l + 1], ap1 = wbv[w][l + 3], ap2 = wbv[w][l + 4];
            unsigned bm2 = 0, bm1 = 0, bp1 = 0, bp2 = 0;
            if (isB) { bm2 = wbv[w][64 + l]; bm1 = wbv[w][65 + l]; bp1 = wbv[w][67 + l]; bp2 = wbv[w][68 + l]; }
            h2 fAh = u2h(fA), fBh = u2h(fB);
            h2 n0 = u2h(am2), n1 = u2h(am1), n2 = u2h(ap1), n3 = u2h(ap2);
            h2 hA = fAh + n0 + n1 + n2 + n3;
            h2 qa = fAh * fAh + n0 * n0 + n1 * n1 + n2 * n2 + n3 * n3;
            float s2A = h2lo(qa) + h2hi(qa);
            h2 m0 = u2h(bm2), m1 = u2h(bm1), m2 = u2h(bp1), m3 = u2h(bp2);
            h2 hB = fBh + m0 + m1 + m2 + m3;
            h2 qb = fBh * fBh + m0 * m0 + m1 * m1 + m2 * m2 + m3 * m3;
            float s2B = h2lo(qb) + h2hi(qb);
            ringA[s % 5] = hA; ringB[s % 5] = hB;
            ringS[s % 5] = pk2(s2A, s2B);
            // vertical 5-sum + variance + period emit at row i = r-2
            if (s >= 4) {
                h2 SA = ringA[0] + ringA[1] + ringA[2] + ringA[3] + ringA[4];
                h2 SB = ringB[0] + ringB[1] + ringB[2] + ringB[3] + ringB[4];
                h2 S2 = ringS[0] + ringS[1] + ringS[2] + ringS[3] + ringS[4];
                float SLA = h2lo(SA), SHA = h2hi(SA);
                float SLB = h2lo(SB), SHB = h2hi(SB);
                float vA = 0.04f * h2lo(S2) - 0.0016f * (SLA * SLA + SHA * SHA);
                float vB = 0.04f * h2hi(S2) - 0.0016f * (SLB * SLB + SHB * SHB);
                vA = fmaxf(vA, 0.f) + 1e-6f;
                vB = fmaxf(vB, 0.f) + 1e-6f;
                prh[s - 4] += pk2(vsqrtf_(vA), vsqrtf_(vB));
            }
            xm1_0 = x0_0; xm1_1 = x0_1; xm1_2 = x0_2;
            x0_0 = xp1_0; x0_1 = xp1_1; x0_2 = xp1_2;
            ra = na; rb = nb;
        }
    }
    size_t base = ((size_t)(cg * 16 + b) * 80 + row0) * 80;
#pragma unroll
    for (int k = 0; k < 10; k++) {
        unsigned eu = h2u(erh[k]), pu = h2u(prh[k]);
        part[base + k * 80 + l] = (eu & 0xFFFFu) | (pu << 16);
        if (isB) part[base + k * 80 + 64 + l] = (eu >> 16) | (pu & 0xFFFF0000u);
    }
}

// ---------------- K2: reduce NCG partials + edge density -> feat_t ch 64..95 ----------------
// grid (8 bands, 16 b), 256 threads
__launch_bounds__(256)
__global__ void density_kernel(const unsigned* __restrict__ part,
                               _Float16* __restrict__ feat_t) {
    __shared__ float E[14][84];
    __shared__ float Hs[14][84];
    __shared__ float Ps[10][80];
    int band = blockIdx.x, b = blockIdx.y, tid = threadIdx.x;
    int r0 = band * 10;
    if (tid < 56) { int rr = tid >> 2, c4 = tid & 3; E[rr][(c4 < 2) ? c4 : 80 + c4] = 0.f; }
    for (int idx = tid; idx < 14 * 80; idx += 256) {
        int rr = idx / 80, j = idx - rr * 80;
        int row = r0 - 2 + rr;
        float e = 0.f, p = 0.f;
        if (row >= 0 && row < 80) {
            size_t off = ((size_t)b * 80 + row) * 80 + j;
#pragma unroll 4
            for (int g = 0; g < NCG; g++) {
                h2 v = u2h(part[(size_t)g * (16 * 80 * 80) + off]);
                e += h2lo(v); p += h2hi(v);
            }
        }
        E[rr][2 + j] = e * (1.f / 256.f);
        if (rr >= 2 && rr < 12) Ps[rr - 2][j] = p * (1.f / 256.f);
    }
    __syncthreads();
    for (int idx = tid; idx < 14 * 80; idx += 256) {
        int rr = idx / 80, j = idx - rr * 80;
        Hs[rr][2 + j] = E[rr][j] + E[rr][j + 1] + E[rr][j + 2] + E[rr][j + 3] + E[rr][j + 4];
    }
    __syncthreads();
    for (int idx = tid; idx < 10 * 80; idx += 256) {
        int k = idx / 80, j = idx - k * 80;
        int rr = k + 2;
        float pool = Hs[rr - 2][2 + j] + Hs[rr - 1][2 + j] + Hs[rr][2 + j]
                   + Hs[rr + 1][2 + j] + Hs[rr + 2][2 + j];
        float ed = E[rr][2 + j] / (pool * 0.04f + 1e-6f);
        _Float16* fp = feat_t + ((size_t)(b * HWN) + (r0 + k) * 80 + j) * 96;
        f16x8 z8 = {};
        f16x8 f8 = {};
        f8[0] = (_Float16)ed; f8[1] = (_Float16)Ps[k][j];
        *reinterpret_cast<f16x8*>(fp + 64) = f8;
        *reinterpret_cast<f16x8*>(fp + 72) = z8;
        *reinterpret_cast<f16x8*>(fp + 80) = z8;
        *reinterpret_cast<f16x8*>(fp + 88) = z8;
    }
}

// ---------------- K3: proj via MFMA (unchanged) ----------------
__launch_bounds__(256)
__global__ void proj_kernel(const float* __restrict__ x,
                            const _Float16* __restrict__ apack,
                            const float* __restrict__ bias1,
                            _Float16* __restrict__ feat_t) {
    __shared__ __align__(16) unsigned char lds[64 * 512];
    int b = blockIdx.y, p0 = blockIdx.x * 64;
    int tid = threadIdx.x, w = tid >> 6, l = tid & 63;

#pragma unroll 4
    for (int i = 0; i < 16; i++) {
        int ch0 = i * 16 + w * 4;
        f16x4 v4;
#pragma unroll
        for (int q = 0; q < 4; q++)
            v4[q] = (_Float16)x[((size_t)(b * CC + ch0 + q)) * HWN + p0 + l];
        int byte = l * 512 + ((ch0 * 2) ^ ((l & 7) << 4));
        *reinterpret_cast<f16x4*>(lds + byte) = v4;
    }
    __syncthreads();

    const f16x8* Ap = reinterpret_cast<const f16x8*>(apack);
    f32x4 acc[4];
#pragma unroll
    for (int ct = 0; ct < 4; ct++) acc[ct] = (f32x4){0.f, 0.f, 0.f, 0.f};

    int kb = 16 * (l >> 4);
#pragma unroll 2
    for (int c = 0; c < 8; c++) {
        f16x8 a = Ap[(c * 4 + w) * 64 + l];
#pragma unroll
        for (int ct = 0; ct < 4; ct++) {
            int byte = (ct * 16 + (l & 15)) * 512 + ((c * 64 + kb) ^ ((l & 7) << 4));
            f16x8 bv = *reinterpret_cast<const f16x8*>(lds + byte);
            acc[ct] = __builtin_amdgcn_mfma_f32_16x16x32_f16(a, bv, acc[ct], 0, 0, 0);
        }
    }

    float b1v[4];
#pragma unroll
    for (int q = 0; q < 4; q++) b1v[q] = bias1[w * 16 + (l >> 4) * 4 + q];
#pragma unroll
    for (int ct = 0; ct < 4; ct++) {
        f16x4 o4;
#pragma unroll
        for (int q = 0; q < 4; q++) {
            float z = acc[ct][q] + b1v[q];
            o4[q] = (_Float16)(z / (1.f + expf(-z)));
        }
        size_t px = (size_t)(b * HWN) + p0 + ct * 16 + (l & 15);
        *reinterpret_cast<f16x4*>(feat_t + px * 96 + w * 16 + (l >> 4) * 4) = o4;
    }
}

// ---------------- K4: fuse via MFMA + epilogue + x*wgt (unchanged) ----------------
#define TROW 256
__launch_bounds__(256)
__global__ void fuse_kernel(const _Float16* __restrict__ feat_t,
                            const _Float16* __restrict__ apack,
                            const float* __restrict__ bias2,
                            const float* __restrict__ fuse2,
                            const float* __restrict__ x,
                            float* __restrict__ out) {
    __shared__ __align__(16) unsigned char tl[108 * TROW];
    __shared__ float R[4 * 4 * 4 * 16];
    __shared__ float wgtbuf[64];
    int b = blockIdx.y, t5 = blockIdx.x;
    int ti = t5 / 5, tj = t5 - ti * 5;
    int i0 = ti * 4, j0 = tj * 16;
    int tid = threadIdx.x, w = tid >> 6, l = tid & 63;

    for (int idx = tid; idx < 1296; idx += 256) {
        int hpx = idx / 12, g = idx - hpx * 12;
        int hr = hpx / 18, hc = hpx - hr * 18;
        int gi = i0 - 1 + hr, gj = j0 - 1 + hc;
        i32x4 val = {0, 0, 0, 0};
        if (gi >= 0 && gi < 80 && gj >= 0 && gj < 80) {
            val = *reinterpret_cast<const i32x4*>(
                feat_t + ((size_t)(b * HWN) + gi * 80 + gj) * 96 + g * 8);
        }
        *reinterpret_cast<i32x4*>(tl + hpx * TROW + ((g * 16) ^ ((hc & 7) << 4))) = val;
    }
    __syncthreads();

    const f16x8* Ap = reinterpret_cast<const f16x8*>(apack);
    f32x4 acc[4];
#pragma unroll
    for (int r = 0; r < 4; r++) acc[r] = (f32x4){0.f, 0.f, 0.f, 0.f};
    int kb = 16 * (l >> 4);

#pragma unroll 1
    for (int t = 0; t < 9; t++) {
        int dy = t / 3, dx = t - dy * 3;
        f16x8 a0 = Ap[((t * 3 + 0) * 4 + w) * 64 + l];
        f16x8 a1 = Ap[((t * 3 + 1) * 4 + w) * 64 + l];
        f16x8 a2 = Ap[((t * 3 + 2) * 4 + w) * 64 + l];
        int hc = (l & 15) + dx;
        int key = (hc & 7) << 4;
#pragma unroll
        for (int r = 0; r < 4; r++) {
            int base = ((r + dy) * 18 + hc) * TROW;
            f16x8 b0 = *reinterpret_cast<const f16x8*>(tl + base + ((0 + kb) ^ key));
            acc[r] = __builtin_amdgcn_mfma_f32_16x16x32_f16(a0, b0, acc[r], 0, 0, 0);
            f16x8 b1_ = *reinterpret_cast<const f16x8*>(tl + base + ((64 + kb) ^ key));
            acc[r] = __builtin_amdgcn_mfma_f32_16x16x32_f16(a1, b1_, acc[r], 0, 0, 0);
            f16x8 b2_ = *reinterpret_cast<const f16x8*>(tl + base + ((128 + kb) ^ key));
            acc[r] = __builtin_amdgcn_mfma_f32_16x16x32_f16(a2, b2_, acc[r], 0, 0, 0);
        }
    }

    float b2v[4], f2v[4];
#pragma unroll
    for (int q = 0; q < 4; q++) {
        int m = w * 16 + (l >> 4) * 4 + q;
        b2v[q] = bias2[m];
        f2v[q] = fuse2[m];
    }
#pragma unroll
    for (int r = 0; r < 4; r++) {
        float p = 0.f;
#pragma unroll
        for (int q = 0; q < 4; q++) {
            float z = acc[r][q] + b2v[q];
            p += f2v[q] * (z / (1.f + expf(-z)));
        }
        R[((w * 4 + r) * 4 + (l >> 4)) * 16 + (l & 15)] = p;
    }
    __syncthreads();
    if (tid < 64) {
        int r = tid >> 4, cc = tid & 15;
        float s = 0.f;
#pragma unroll
        for (int w2 = 0; w2 < 4; w2++)
#pragma unroll
            for (int g2 = 0; g2 < 4; g2++)
                s += R[((w2 * 4 + r) * 4 + g2) * 16 + cc];
        wgtbuf[tid] = 1.f / (1.f + expf(-s));
    }
    __syncthreads();

    int r = l >> 4, cc = l & 15;
    float wgt = wgtbuf[l];
    size_t base = (size_t)b * CC * HWN + (size_t)((i0 + r) * 80 + j0 + cc);
    const float* xp = x + base;
    float* op = out + base;
#pragma unroll 4
    for (int ch = w * 64; ch < w * 64 + 64; ch++) {
        op[(size_t)ch * HWN] = xp[(size_t)ch * HWN] * wgt;
    }
}

// ---------------- launch ----------------
extern "C" void kernel_launch(void* const* d_in, const int* in_sizes, int n_in,
                              void* d_out, int out_size, void* d_ws, size_t ws_size,
                              hipStream_t stream) {
    (void)in_sizes; (void)n_in; (void)out_size; (void)ws_size;
    const float* x       = (const float*)d_in[0];
    const float* proj_w  = (const float*)d_in[1];
    const float* bn1_g   = (const float*)d_in[2];
    const float* bn1_b   = (const float*)d_in[3];
    const float* bn1_m   = (const float*)d_in[4];
    const float* bn1_v   = (const float*)d_in[5];
    const float* fuse1_w = (const float*)d_in[6];
    const float* bn2_g   = (const float*)d_in[7];
    const float* bn2_b   = (const float*)d_in[8];
    const float* bn2_m   = (const float*)d_in[9];
    const float* bn2_v   = (const float*)d_in[10];
    const float* fuse2_w = (const float*)d_in[11];
    float* out = (float*)d_out;

    float* ws = (float*)d_ws;
    unsigned* part        = (unsigned*)ws;               // 64*16*6400 = 6,553,600 uints
    _Float16* feat_t      = (_Float16*)(ws + 6553600);   // 16*6400*96 f16 = 4,915,200 f
    _Float16* apack_proj  = (_Float16*)(ws + 11468800);  // 16384 f16
    _Float16* apack_fuse  = (_Float16*)(ws + 11476992);  // 55296 f16
    float*    bias1       = ws + 11504640;
    float*    bias2       = ws + 11504704;

    prep_kernel<<<288, 256, 0, stream>>>(proj_w, bn1_g, bn1_b, bn1_m, bn1_v,
                                         fuse1_w, bn2_g, bn2_b, bn2_m, bn2_v,
                                         apack_proj, apack_fuse, bias1, bias2);
    edge_period_kernel<<<dim3(NCG, 16), 512, 0, stream>>>(x, part);
    density_kernel<<<dim3(8, 16), 256, 0, stream>>>(part, feat_t);
    proj_kernel<<<dim3(100, 16), 256, 0, stream>>>(x, apack_proj, bias1, feat_t);
    fuse_kernel<<<dim3(100, 16), 256, 0, stream>>>(feat_t, apack_fuse,
                                                   bias2, fuse2_w, x, out);
}

// Round 17
// 218.094 us; speedup vs baseline: 2.9950x; 1.2153x over previous
//
#include <hip/hip_runtime.h>
#include <hip/hip_bf16.h>
#include <math.h>

#define HWN 6400
#define CC 256
#define MIDN 64

typedef _Float16 f16x8 __attribute__((ext_vector_type(8)));
typedef _Float16 f16x4 __attribute__((ext_vector_type(4)));
typedef _Float16 h2    __attribute__((ext_vector_type(2)));
typedef float    f32x4 __attribute__((ext_vector_type(4)));
typedef int      i32x4 __attribute__((ext_vector_type(4)));

__device__ __forceinline__ h2 pk2(float a, float b) {
    return __builtin_bit_cast(h2, __builtin_amdgcn_cvt_pkrtz(a, b));
}
__device__ __forceinline__ float h2lo(h2 v) { return (float)v[0]; }
__device__ __forceinline__ float h2hi(h2 v) { return (float)v[1]; }
__device__ __forceinline__ unsigned h2u(h2 v) { return __builtin_bit_cast(unsigned, v); }
__device__ __forceinline__ h2 u2h(unsigned u) { return __builtin_bit_cast(h2, u); }
__device__ __forceinline__ float vsqrtf_(float x) { float r; asm("v_sqrt_f32 %0, %1" : "=v"(r) : "v"(x)); return r; }

// ---------------- K0: fold BN, pack MFMA A-fragments (fp16) ----------------
__global__ void prep_kernel(const float* __restrict__ proj_w,
                            const float* __restrict__ g1, const float* __restrict__ b1,
                            const float* __restrict__ m1, const float* __restrict__ v1,
                            const float* __restrict__ f1w,
                            const float* __restrict__ g2, const float* __restrict__ b2,
                            const float* __restrict__ m2, const float* __restrict__ v2,
                            _Float16* __restrict__ apack_proj,
                            _Float16* __restrict__ apack_fuse,
                            float* __restrict__ bias1, float* __restrict__ bias2) {
    int gid = blockIdx.x * blockDim.x + threadIdx.x;
    int stride = gridDim.x * blockDim.x;
    if (gid < MIDN) {
        float s1 = g1[gid] * rsqrtf(v1[gid] + 1e-5f);
        bias1[gid] = b1[gid] - m1[gid] * s1;
        float s2 = g2[gid] * rsqrtf(v2[gid] + 1e-5f);
        bias2[gid] = b2[gid] - m2[gid] * s2;
    }
    for (int i = gid; i < 8 * 4 * 64 * 8; i += stride) {
        int j = i & 7, lane = (i >> 3) & 63, w = (i >> 9) & 3, c = i >> 11;
        int m = w * 16 + (lane & 15);
        int ch = c * 32 + (lane >> 4) * 8 + j;
        float s1 = g1[m] * rsqrtf(v1[m] + 1e-5f);
        apack_proj[i] = (_Float16)(proj_w[m * CC + ch] * s1);
    }
    for (int i = gid; i < 9 * 3 * 4 * 64 * 8; i += stride) {
        int j = i & 7, lane = (i >> 3) & 63, w = (i >> 9) & 3;
        int tc = i >> 11; int c = tc % 3, t = tc / 3;
        int m = w * 16 + (lane & 15);
        int ch = c * 32 + (lane >> 4) * 8 + j;
        float s2 = g2[m] * rsqrtf(v2[m] + 1e-5f);
        float v = 0.f;
        if (ch < 66) v = f1w[(m * 66 + ch) * 9 + t] * s2;
        apack_fuse[i] = (_Float16)v;
    }
}

// ---------------- K1A: edge+period, 1 channel/block, immediate stores ----------------
// grid (256 ch, 16 b), 256 thr = 4 waves; wave w owns rows [20w, 20w+20);
// lane l owns cols {l, 64+l(l<16)}. NO accumulator arrays: {er,pr} stored to
// part[ch][b][row][col] as f16x2 at each emit step (fire-and-forget stores,
// no rmw dependency). wb volatile (same-wave cross-lane LDS dep).
__launch_bounds__(256, 4)
__global__ void edge_period_pc_kernel(const float* __restrict__ x,
                                      unsigned* __restrict__ part) {
    __shared__ unsigned wb[4][88];
    volatile unsigned (*wbv)[88] = wb;
    int tid = threadIdx.x;
    int w = tid >> 6, l = tid & 63;
    int b = blockIdx.y, cg = blockIdx.x;
    int row0 = w * 20;
    int im1 = (l + 63) & 63, ip1 = (l + 1) & 63;
    bool is0 = (l == 0), is63 = (l == 63), isB = (l < 16);

    if (l < 4) wbv[w][(l < 2) ? l : 80 + l] = 0u;   // zero pad cols idx 0,1,82,83

    float cwA = (l <= 0) ? 1.f : ((l >= 79) ? 0.f : (0.99375f - 0.0125f * (float)l));
    int cB = 64 + l;
    float cwB = (cB >= 79) ? 0.f : (0.99375f - 0.0125f * (float)cB);
    h2 v_pk = pk2(0.5f * cwA, 0.5f * cwB);
    h2 u_pk = pk2(0.5f * (1.f - cwA), 0.5f * (1.f - cwB));

    h2 ering[2];
    ering[0] = u2h(0u); ering[1] = u2h(0u);

    const float* xch = x + ((size_t)(b * CC + cg)) * HWN;
    unsigned* pout = part + ((size_t)(cg * 16 + b)) * HWN;

    auto rawload = [&](int rr, float& a, float& bb) {
        a = 0.f; bb = 0.f;
        if (rr >= 0 && rr < 80) {
            a = xch[rr * 80 + l];
            if (isB) bb = xch[rr * 80 + 64 + l];
        }
    };
    auto mktrip = [&](float a, float bb, h2& t0, h2& t1, h2& t2) {
        h2 xc = pk2(a, bb);
        int xi = __builtin_bit_cast(int, xc);
        unsigned um = (unsigned)__shfl(xi, im1);
        unsigned up = (unsigned)__shfl(xi, ip1);
        um = is0 ? ((um & 0xFFFFu) << 16) : um;   // lane0: {0, col63}
        up = is63 ? (up >> 16) : up;              // lane63: {col64, 0}
        t0 = u2h(um); t1 = xc; t2 = u2h(up);
    };
    h2 xm1_0, xm1_1, xm1_2, x0_0, x0_1, x0_2, xp1_0, xp1_1, xp1_2;
    float ta, tb, ra, rb, na, nb;
    rawload(row0 - 3, ta, tb);
    rawload(row0 - 2, ra, rb);
    mktrip(ta, tb, xm1_0, xm1_1, xm1_2);
    mktrip(ra, rb, x0_0, x0_1, x0_2);
    rawload(row0 - 1, ra, rb);          // raw row for s=0's xp1
    // seam init: haar at row pair (row0-3, row0-2)
    h2 lhc_p, hlc_p;
    {
        h2 sa = xm1_0 + x0_0, sb = xm1_1 + x0_1, sc2 = xm1_2 + x0_2;
        h2 da = xm1_0 - x0_0, db = xm1_1 - x0_1, dc = xm1_2 - x0_2;
        lhc_p = u_pk * (sa - sb) + v_pk * (sb - sc2);
        hlc_p = u_pk * (da + db) + v_pk * (db + dc);
    }
    h2 ringA[5], ringB[5], ringS[5];
#pragma unroll
    for (int s = 0; s < 24; s++) {
        int r = row0 - 2 + s;
        if (s < 23) rawload(row0 + s, na, nb);
        mktrip(ra, rb, xp1_0, xp1_1, xp1_2);
        // Sobel (rows row0..row0+19 at s in [2,22))
        h2 er_new = u2h(0u);
        if (s >= 2 && s < 22) {
            h2 gx = (xm1_2 - xm1_0) + (x0_2 - x0_0) + (x0_2 - x0_0) + (xp1_2 - xp1_0);
            h2 gy = (xp1_0 - xm1_0) + (xp1_1 - xm1_1) + (xp1_1 - xm1_1) + (xp1_2 - xm1_2);
            h2 g2v = gx * gx + gy * gy;
            er_new = pk2(vsqrtf_(h2lo(g2v)) * 0.125f, vsqrtf_(h2hi(g2v)) * 0.125f);
        }
        // Haar row pair (r, r+1) -> column-resized lh/hl, then row-resize
        h2 sa = x0_0 + xp1_0, sb = x0_1 + xp1_1, sc2 = x0_2 + xp1_2;
        h2 da = x0_0 - xp1_0, db = x0_1 - xp1_1, dc = x0_2 - xp1_2;
        h2 lhc = u_pk * (sa - sb) + v_pk * (sb - sc2);
        h2 hlc = u_pk * (da + db) + v_pk * (db + dc);
        float cw = (r <= 0) ? 1.f : ((r >= 79) ? 0.f : (0.99375f - 0.0125f * (float)r));
        h2 cwp = pk2(cw, cw), pwp = pk2(1.f - cw, 1.f - cw);
        h2 lhr = pwp * lhc_p + cwp * lhc;
        h2 hlr = pwp * hlc_p + cwp * hlc;
        lhc_p = lhc; hlc_p = hlc;
        unsigned lu = h2u(lhr), hu = h2u(hlr);
        unsigned fA = (lu & 0xFFFFu) | (hu << 16);           // {lh,hl} col l
        unsigned fB = (lu >> 16) | (hu & 0xFFFF0000u);       // {lh,hl} col 64+l
        bool fv = (r >= 0) && (r < 80);
        if (!fv) { fA = 0u; fB = 0u; }
        // horizontal 5-sum via per-wave LDS row (volatile keeps order)
        wbv[w][2 + l] = fA;
        if (isB) wbv[w][66 + l] = fB;
        unsigned am2 = wbv[w][l], am1 = wbv[w][l + 1], ap1 = wbv[w][l + 3], ap2 = wbv[w][l + 4];
        unsigned bm2 = 0, bm1 = 0, bp1 = 0, bp2 = 0;
        if (isB) { bm2 = wbv[w][64 + l]; bm1 = wbv[w][65 + l]; bp1 = wbv[w][67 + l]; bp2 = wbv[w][68 + l]; }
        h2 fAh = u2h(fA), fBh = u2h(fB);
        h2 n0 = u2h(am2), n1 = u2h(am1), n2 = u2h(ap1), n3 = u2h(ap2);
        h2 hA = fAh + n0 + n1 + n2 + n3;
        h2 qa = fAh * fAh + n0 * n0 + n1 * n1 + n2 * n2 + n3 * n3;
        float s2A = h2lo(qa) + h2hi(qa);
        h2 m0 = u2h(bm2), m1 = u2h(bm1), m2 = u2h(bp1), m3 = u2h(bp2);
        h2 hB = fBh + m0 + m1 + m2 + m3;
        h2 qb = fBh * fBh + m0 * m0 + m1 * m1 + m2 * m2 + m3 * m3;
        float s2B = h2lo(qb) + h2hi(qb);
        ringA[s % 5] = hA; ringB[s % 5] = hB;
        ringS[s % 5] = pk2(s2A, s2B);
        // vertical 5-sum + variance + IMMEDIATE store for row s-4
        if (s >= 4) {
            h2 SA = ringA[0] + ringA[1] + ringA[2] + ringA[3] + ringA[4];
            h2 SB = ringB[0] + ringB[1] + ringB[2] + ringB[3] + ringB[4];
            h2 S2 = ringS[0] + ringS[1] + ringS[2] + ringS[3] + ringS[4];
            float SLA = h2lo(SA), SHA = h2hi(SA);
            float SLB = h2lo(SB), SHB = h2hi(SB);
            float vA = 0.04f * h2lo(S2) - 0.0016f * (SLA * SLA + SHA * SHA);
            float vB = 0.04f * h2hi(S2) - 0.0016f * (SLB * SLB + SHB * SHB);
            vA = fmaxf(vA, 0.f) + 1e-6f;
            vB = fmaxf(vB, 0.f) + 1e-6f;
            unsigned eu = h2u(ering[s & 1]);    // er for row s-4 (stored at s-2)
            unsigned pu = h2u(pk2(vsqrtf_(vA), vsqrtf_(vB)));
            int orow = row0 + s - 4;
            pout[orow * 80 + l] = (eu & 0xFFFFu) | (pu << 16);
            if (isB) pout[orow * 80 + 64 + l] = (eu >> 16) | (pu & 0xFFFF0000u);
        }
        if (s >= 2 && s < 22) ering[s & 1] = er_new;   // after old er consumed
        xm1_0 = x0_0; xm1_1 = x0_1; xm1_2 = x0_2;
        x0_0 = xp1_0; x0_1 = xp1_1; x0_2 = xp1_2;
        ra = na; rb = nb;
    }
}

// ---------------- K1B: fallback (R16): 4 ch/block accumulate ----------------
#define NCGB 64
__launch_bounds__(512, 4)
__global__ void edge_period_acc_kernel(const float* __restrict__ x,
                                       unsigned* __restrict__ part) {
    __shared__ unsigned wb[8][88];
    volatile unsigned (*wbv)[88] = wb;
    int tid = threadIdx.x;
    int w = tid >> 6, l = tid & 63;
    int b = blockIdx.y, cg = blockIdx.x;
    int row0 = w * 10;
    int im1 = (l + 63) & 63, ip1 = (l + 1) & 63;
    bool is0 = (l == 0), is63 = (l == 63), isB = (l < 16);

    if (l < 4) wbv[w][(l < 2) ? l : 80 + l] = 0u;

    float cwA = (l <= 0) ? 1.f : ((l >= 79) ? 0.f : (0.99375f - 0.0125f * (float)l));
    int cB = 64 + l;
    float cwB = (cB >= 79) ? 0.f : (0.99375f - 0.0125f * (float)cB);
    h2 v_pk = pk2(0.5f * cwA, 0.5f * cwB);
    h2 u_pk = pk2(0.5f * (1.f - cwA), 0.5f * (1.f - cwB));

    h2 erh[10], prh[10];
#pragma unroll
    for (int k = 0; k < 10; k++) { erh[k] = u2h(0u); prh[k] = u2h(0u); }

#pragma unroll 1
    for (int ch = 0; ch < 4; ch++) {
        const float* xch = x + ((size_t)(b * CC + cg * 4 + ch)) * HWN;
        auto rawload = [&](int rr, float& a, float& bb) {
            a = 0.f; bb = 0.f;
            if (rr >= 0 && rr < 80) {
                a = xch[rr * 80 + l];
                if (isB) bb = xch[rr * 80 + 64 + l];
            }
        };
        auto mktrip = [&](float a, float bb, h2& t0, h2& t1, h2& t2) {
            h2 xc = pk2(a, bb);
            int xi = __builtin_bit_cast(int, xc);
            unsigned um = (unsigned)__shfl(xi, im1);
            unsigned up = (unsigned)__shfl(xi, ip1);
            um = is0 ? ((um & 0xFFFFu) << 16) : um;
            up = is63 ? (up >> 16) : up;
            t0 = u2h(um); t1 = xc; t2 = u2h(up);
        };
        h2 xm1_0, xm1_1, xm1_2, x0_0, x0_1, x0_2, xp1_0, xp1_1, xp1_2;
        float ta, tb, ra, rb, na, nb;
        rawload(row0 - 3, ta, tb);
        rawload(row0 - 2, ra, rb);
        mktrip(ta, tb, xm1_0, xm1_1, xm1_2);
        mktrip(ra, rb, x0_0, x0_1, x0_2);
        rawload(row0 - 1, ra, rb);
        h2 lhc_p, hlc_p;
        {
            h2 sa = xm1_0 + x0_0, sb = xm1_1 + x0_1, sc2 = xm1_2 + x0_2;
            h2 da = xm1_0 - x0_0, db = xm1_1 - x0_1, dc = xm1_2 - x0_2;
            lhc_p = u_pk * (sa - sb) + v_pk * (sb - sc2);
            hlc_p = u_pk * (da + db) + v_pk * (db + dc);
        }
        h2 ringA[5], ringB[5], ringS[5];
#pragma unroll
        for (int s = 0; s < 14; s++) {
            int r = row0 - 2 + s;
            if (s < 13) rawload(row0 + s, na, nb);
            mktrip(ra, rb, xp1_0, xp1_1, xp1_2);
            if (s >= 2 && s < 12) {
                h2 gx = (xm1_2 - xm1_0) + (x0_2 - x0_0) + (x0_2 - x0_0) + (xp1_2 - xp1_0);
                h2 gy = (xp1_0 - xm1_0) + (xp1_1 - xm1_1) + (xp1_1 - xm1_1) + (xp1_2 - xm1_2);
                h2 g2v = gx * gx + gy * gy;
                erh[s - 2] += pk2(vsqrtf_(h2lo(g2v)) * 0.125f, vsqrtf_(h2hi(g2v)) * 0.125f);
            }
            h2 sa = x0_0 + xp1_0, sb = x0_1 + xp1_1, sc2 = x0_2 + xp1_2;
            h2 da = x0_0 - xp1_0, db = x0_1 - xp1_1, dc = x0_2 - xp1_2;
            h2 lhc = u_pk * (sa - sb) + v_pk * (sb - sc2);
            h2 hlc = u_pk * (da + db) + v_pk * (db + dc);
            float cw = (r <= 0) ? 1.f : ((r >= 79) ? 0.f : (0.99375f - 0.0125f * (float)r));
            h2 cwp = pk2(cw, cw), pwp = pk2(1.f - cw, 1.f - cw);
            h2 lhr = pwp * lhc_p + cwp * lhc;
            h2 hlr = pwp * hlc_p + cwp * hlc;
            lhc_p = lhc; hlc_p = hlc;
            unsigned lu = h2u(lhr), hu = h2u(hlr);
            unsigned fA = (lu & 0xFFFFu) | (hu << 16);
            unsigned fB = (lu >> 16) | (hu & 0xFFFF0000u);
            bool fv = (r >= 0) && (r < 80);
            if (!fv) { fA = 0u; fB = 0u; }
            wbv[w][2 + l] = fA;
            if (isB) wbv[w][66 + l] = fB;
            unsigned am2 = wbv[w][l], am1 = wbv[w][l + 1], ap1 = wbv[w][l + 3], ap2 = wbv[w][l + 4];
            unsigned bm2 = 0, bm1 = 0, bp1 = 0, bp2 = 0;
            if (isB) { bm2 = wbv[w][64 + l]; bm1 = wbv[w][65 + l]; bp1 = wbv[w][67 + l]; bp2 = wbv[w][68 + l]; }
            h2 fAh = u2h(fA), fBh = u2h(fB);
            h2 n0 = u2h(am2), n1 = u2h(am1), n2 = u2h(ap1), n3 = u2h(ap2);
            h2 hA = fAh + n0 + n1 + n2 + n3;
            h2 qa = fAh * fAh + n0 * n0 + n1 * n1 + n2 * n2 + n3 * n3;
            float s2A = h2lo(qa) + h2hi(qa);
            h2 m0 = u2h(bm2), m1 = u2h(bm1), m2 = u2h(bp1), m3 = u2h(bp2);
            h2 hB = fBh + m0 + m1 + m2 + m3;
            h2 qb = fBh * fBh + m0 * m0 + m1 * m1 + m2 * m2 + m3 * m3;
            float s2B = h2lo(qb) + h2hi(qb);
            ringA[s % 5] = hA; ringB[s % 5] = hB;
            ringS[s % 5] = pk2(s2A, s2B);
            if (s >= 4) {
                h2 SA = ringA[0] + ringA[1] + ringA[2] + ringA[3] + ringA[4];
                h2 SB = ringB[0] + ringB[1] + ringB[2] + ringB[3] + ringB[4];
                h2 S2 = ringS[0] + ringS[1] + ringS[2] + ringS[3] + ringS[4];
                float SLA = h2lo(SA), SHA = h2hi(SA);
                float SLB = h2lo(SB), SHB = h2hi(SB);
                float vA = 0.04f * h2lo(S2) - 0.0016f * (SLA * SLA + SHA * SHA);
                float vB = 0.04f * h2hi(S2) - 0.0016f * (SLB * SLB + SHB * SHB);
                vA = fmaxf(vA, 0.f) + 1e-6f;
                vB = fmaxf(vB, 0.f) + 1e-6f;
                prh[s - 4] += pk2(vsqrtf_(vA), vsqrtf_(vB));
            }
            xm1_0 = x0_0; xm1_1 = x0_1; xm1_2 = x0_2;
            x0_0 = xp1_0; x0_1 = xp1_1; x0_2 = xp1_2;
            ra = na; rb = nb;
        }
    }
    size_t base = ((size_t)(cg * 16 + b) * 80 + row0) * 80;
#pragma unroll
    for (int k = 0; k < 10; k++) {
        unsigned eu = h2u(erh[k]), pu = h2u(prh[k]);
        part[base + k * 80 + l] = (eu & 0xFFFFu) | (pu << 16);
        if (isB) part[base + k * 80 + 64 + l] = (eu >> 16) | (pu & 0xFFFF0000u);
    }
}

// ---------------- K2a: sum channel partials -> f32 esum/psum ----------------
// grid (25, 16), 256 thr; thread = pixel
__launch_bounds__(256)
__global__ void chsum_kernel(const unsigned* __restrict__ part,
                             float* __restrict__ esum, float* __restrict__ psum,
                             int ngroups) {
    int b = blockIdx.y;
    int p = blockIdx.x * 256 + threadIdx.x;
    float e = 0.f, pp = 0.f;
#pragma unroll 8
    for (int g = 0; g < ngroups; g++) {
        h2 v = u2h(part[((size_t)(g * 16 + b)) * HWN + p]);
        e += h2lo(v); pp += h2hi(v);
    }
    esum[b * HWN + p] = e;
    psum[b * HWN + p] = pp;
}

// ---------------- K2b: edge density + write feat_t ch 64..95 ----------------
__launch_bounds__(256)
__global__ void density_kernel(const float* __restrict__ esum,
                               const float* __restrict__ psum,
                               _Float16* __restrict__ feat_t) {
    __shared__ float E[14][84];
    __shared__ float Hs[14][84];
    __shared__ float Ps[10][80];
    int band = blockIdx.x, b = blockIdx.y, tid = threadIdx.x;
    int r0 = band * 10;
    if (tid < 56) { int rr = tid >> 2, c4 = tid & 3; E[rr][(c4 < 2) ? c4 : 80 + c4] = 0.f; }
    for (int idx = tid; idx < 14 * 80; idx += 256) {
        int rr = idx / 80, j = idx - rr * 80;
        int row = r0 - 2 + rr;
        float e = 0.f, p = 0.f;
        if (row >= 0 && row < 80) {
            size_t off = (size_t)b * HWN + row * 80 + j;
            e = esum[off]; p = psum[off];
        }
        E[rr][2 + j] = e * (1.f / 256.f);
        if (rr >= 2 && rr < 12) Ps[rr - 2][j] = p * (1.f / 256.f);
    }
    __syncthreads();
    for (int idx = tid; idx < 14 * 80; idx += 256) {
        int rr = idx / 80, j = idx - rr * 80;
        Hs[rr][2 + j] = E[rr][j] + E[rr][j + 1] + E[rr][j + 2] + E[rr][j + 3] + E[rr][j + 4];
    }
    __syncthreads();
    for (int idx = tid; idx < 10 * 80; idx += 256) {
        int k = idx / 80, j = idx - k * 80;
        int rr = k + 2;
        float pool = Hs[rr - 2][2 + j] + Hs[rr - 1][2 + j] + Hs[rr][2 + j]
                   + Hs[rr + 1][2 + j] + Hs[rr + 2][2 + j];
        float ed = E[rr][2 + j] / (pool * 0.04f + 1e-6f);
        _Float16* fp = feat_t + ((size_t)(b * HWN) + (r0 + k) * 80 + j) * 96;
        f16x8 z8 = {};
        f16x8 f8 = {};
        f8[0] = (_Float16)ed; f8[1] = (_Float16)Ps[k][j];
        *reinterpret_cast<f16x8*>(fp + 64) = f8;
        *reinterpret_cast<f16x8*>(fp + 72) = z8;
        *reinterpret_cast<f16x8*>(fp + 80) = z8;
        *reinterpret_cast<f16x8*>(fp + 88) = z8;
    }
}

// ---------------- K3: proj via MFMA ----------------
__launch_bounds__(256)
__global__ void proj_kernel(const float* __restrict__ x,
                            const _Float16* __restrict__ apack,
                            const float* __restrict__ bias1,
                            _Float16* __restrict__ feat_t) {
    __shared__ __align__(16) unsigned char lds[64 * 512];
    int b = blockIdx.y, p0 = blockIdx.x * 64;
    int tid = threadIdx.x, w = tid >> 6, l = tid & 63;

#pragma unroll 4
    for (int i = 0; i < 16; i++) {
        int ch0 = i * 16 + w * 4;
        f16x4 v4;
#pragma unroll
        for (int q = 0; q < 4; q++)
            v4[q] = (_Float16)x[((size_t)(b * CC + ch0 + q)) * HWN + p0 + l];
        int byte = l * 512 + ((ch0 * 2) ^ ((l & 7) << 4));
        *reinterpret_cast<f16x4*>(lds + byte) = v4;
    }
    __syncthreads();

    const f16x8* Ap = reinterpret_cast<const f16x8*>(apack);
    f32x4 acc[4];
#pragma unroll
    for (int ct = 0; ct < 4; ct++) acc[ct] = (f32x4){0.f, 0.f, 0.f, 0.f};

    int kb = 16 * (l >> 4);
#pragma unroll 2
    for (int c = 0; c < 8; c++) {
        f16x8 a = Ap[(c * 4 + w) * 64 + l];
#pragma unroll
        for (int ct = 0; ct < 4; ct++) {
            int byte = (ct * 16 + (l & 15)) * 512 + ((c * 64 + kb) ^ ((l & 7) << 4));
            f16x8 bv = *reinterpret_cast<const f16x8*>(lds + byte);
            acc[ct] = __builtin_amdgcn_mfma_f32_16x16x32_f16(a, bv, acc[ct], 0, 0, 0);
        }
    }

    float b1v[4];
#pragma unroll
    for (int q = 0; q < 4; q++) b1v[q] = bias1[w * 16 + (l >> 4) * 4 + q];
#pragma unroll
    for (int ct = 0; ct < 4; ct++) {
        f16x4 o4;
#pragma unroll
        for (int q = 0; q < 4; q++) {
            float z = acc[ct][q] + b1v[q];
            o4[q] = (_Float16)(z / (1.f + expf(-z)));
        }
        size_t px = (size_t)(b * HWN) + p0 + ct * 16 + (l & 15);
        *reinterpret_cast<f16x4*>(feat_t + px * 96 + w * 16 + (l >> 4) * 4) = o4;
    }
}

// ---------------- K4: fuse via MFMA + epilogue + x*wgt ----------------
#define TROW 256
__launch_bounds__(256)
__global__ void fuse_kernel(const _Float16* __restrict__ feat_t,
                            const _Float16* __restrict__ apack,
                            const float* __restrict__ bias2,
                            const float* __restrict__ fuse2,
                            const float* __restrict__ x,
                            float* __restrict__ out) {
    __shared__ __align__(16) unsigned char tl[108 * TROW];
    __shared__ float R[4 * 4 * 4 * 16];
    __shared__ float wgtbuf[64];
    int b = blockIdx.y, t5 = blockIdx.x;
    int ti = t5 / 5, tj = t5 - ti * 5;
    int i0 = ti * 4, j0 = tj * 16;
    int tid = threadIdx.x, w = tid >> 6, l = tid & 63;

    for (int idx = tid; idx < 1296; idx += 256) {
        int hpx = idx / 12, g = idx - hpx * 12;
        int hr = hpx / 18, hc = hpx - hr * 18;
        int gi = i0 - 1 + hr, gj = j0 - 1 + hc;
        i32x4 val = {0, 0, 0, 0};
        if (gi >= 0 && gi < 80 && gj >= 0 && gj < 80) {
            val = *reinterpret_cast<const i32x4*>(
                feat_t + ((size_t)(b * HWN) + gi * 80 + gj) * 96 + g * 8);
        }
        *reinterpret_cast<i32x4*>(tl + hpx * TROW + ((g * 16) ^ ((hc & 7) << 4))) = val;
    }
    __syncthreads();

    const f16x8* Ap = reinterpret_cast<const f16x8*>(apack);
    f32x4 acc[4];
#pragma unroll
    for (int r = 0; r < 4; r++) acc[r] = (f32x4){0.f, 0.f, 0.f, 0.f};
    int kb = 16 * (l >> 4);

#pragma unroll 1
    for (int t = 0; t < 9; t++) {
        int dy = t / 3, dx = t - dy * 3;
        f16x8 a0 = Ap[((t * 3 + 0) * 4 + w) * 64 + l];
        f16x8 a1 = Ap[((t * 3 + 1) * 4 + w) * 64 + l];
        f16x8 a2 = Ap[((t * 3 + 2) * 4 + w) * 64 + l];
        int hc = (l & 15) + dx;
        int key = (hc & 7) << 4;
#pragma unroll
        for (int r = 0; r < 4; r++) {
            int base = ((r + dy) * 18 + hc) * TROW;
            f16x8 b0 = *reinterpret_cast<const f16x8*>(tl + base + ((0 + kb) ^ key));
            acc[r] = __builtin_amdgcn_mfma_f32_16x16x32_f16(a0, b0, acc[r], 0, 0, 0);
            f16x8 b1_ = *reinterpret_cast<const f16x8*>(tl + base + ((64 + kb) ^ key));
            acc[r] = __builtin_amdgcn_mfma_f32_16x16x32_f16(a1, b1_, acc[r], 0, 0, 0);
            f16x8 b2_ = *reinterpret_cast<const f16x8*>(tl + base + ((128 + kb) ^ key));
            acc[r] = __builtin_amdgcn_mfma_f32_16x16x32_f16(a2, b2_, acc[r], 0, 0, 0);
        }
    }

    float b2v[4], f2v[4];
#pragma unroll
    for (int q = 0; q < 4; q++) {
        int m = w * 16 + (l >> 4) * 4 + q;
        b2v[q] = bias2[m];
        f2v[q] = fuse2[m];
    }
#pragma unroll
    for (int r = 0; r < 4; r++) {
        float p = 0.f;
#pragma unroll
        for (int q = 0; q < 4; q++) {
            float z = acc[r][q] + b2v[q];
            p += f2v[q] * (z / (1.f + expf(-z)));
        }
        R[((w * 4 + r) * 4 + (l >> 4)) * 16 + (l & 15)] = p;
    }
    __syncthreads();
    if (tid < 64) {
        int r = tid >> 4, cc = tid & 15;
        float s = 0.f;
#pragma unroll
        for (int w2 = 0; w2 < 4; w2++)
#pragma unroll
            for (int g2 = 0; g2 < 4; g2++)
                s += R[((w2 * 4 + r) * 4 + g2) * 16 + cc];
        wgtbuf[tid] = 1.f / (1.f + expf(-s));
    }
    __syncthreads();

    int r = l >> 4, cc = l & 15;
    float wgt = wgtbuf[l];
    size_t base = (size_t)b * CC * HWN + (size_t)((i0 + r) * 80 + j0 + cc);
    const float* xp = x + base;
    float* op = out + base;
#pragma unroll 4
    for (int ch = w * 64; ch < w * 64 + 64; ch++) {
        op[(size_t)ch * HWN] = xp[(size_t)ch * HWN] * wgt;
    }
}

// ---------------- launch ----------------
extern "C" void kernel_launch(void* const* d_in, const int* in_sizes, int n_in,
                              void* d_out, int out_size, void* d_ws, size_t ws_size,
                              hipStream_t stream) {
    (void)in_sizes; (void)n_in; (void)out_size;
    const float* x       = (const float*)d_in[0];
    const float* proj_w  = (const float*)d_in[1];
    const float* bn1_g   = (const float*)d_in[2];
    const float* bn1_b   = (const float*)d_in[3];
    const float* bn1_m   = (const float*)d_in[4];
    const float* bn1_v   = (const float*)d_in[5];
    const float* fuse1_w = (const float*)d_in[6];
    const float* bn2_g   = (const float*)d_in[7];
    const float* bn2_b   = (const float*)d_in[8];
    const float* bn2_m   = (const float*)d_in[9];
    const float* bn2_v   = (const float*)d_in[10];
    const float* fuse2_w = (const float*)d_in[11];
    float* out = (float*)d_out;

    // path A (per-channel partials) needs ~125.5 MB of workspace
    const size_t needA = (size_t)(256 * 16 * HWN) * 4   // part
                       + (size_t)2 * 16 * HWN * 4       // esum/psum
                       + (size_t)16 * HWN * 96 * 2      // feat_t
                       + (16384 + 55296) * 2 + 1024;    // apacks + biases
    bool useA = ws_size >= needA;
    int ngroups = useA ? 256 : NCGB;

    float* ws = (float*)d_ws;
    size_t partN = (size_t)ngroups * 16 * HWN;          // uints
    unsigned* part        = (unsigned*)ws;
    float*    esum        = ws + partN;
    float*    psum        = esum + 16 * HWN;
    _Float16* feat_t      = (_Float16*)(psum + 16 * HWN);
    float*    after_feat  = (float*)(feat_t + (size_t)16 * HWN * 96);
    _Float16* apack_proj  = (_Float16*)after_feat;
    _Float16* apack_fuse  = apack_proj + 16384;
    float*    bias1       = (float*)(apack_fuse + 55296);
    float*    bias2       = bias1 + 64;

    prep_kernel<<<288, 256, 0, stream>>>(proj_w, bn1_g, bn1_b, bn1_m, bn1_v,
                                         fuse1_w, bn2_g, bn2_b, bn2_m, bn2_v,
                                         apack_proj, apack_fuse, bias1, bias2);
    if (useA) {
        edge_period_pc_kernel<<<dim3(256, 16), 256, 0, stream>>>(x, part);
    } else {
        edge_period_acc_kernel<<<dim3(NCGB, 16), 512, 0, stream>>>(x, part);
    }
    chsum_kernel<<<dim3(25, 16), 256, 0, stream>>>(part, esum, psum, ngroups);
    density_kernel<<<dim3(8, 16), 256, 0, stream>>>(esum, psum, feat_t);
    proj_kernel<<<dim3(100, 16), 256, 0, stream>>>(x, apack_proj, bias1, feat_t);
    fuse_kernel<<<dim3(100, 16), 256, 0, stream>>>(feat_t, apack_fuse,
                                                   bias2, fuse2_w, x, out);
}